// Round 6
// baseline (1748.140 us; speedup 1.0000x reference)
//
#include <hip/hip_runtime.h>
#include <math.h>

// Problem constants
#define BB 32768
#define DD 64
#define CC 64
#define HH 1024
#define LL 6
#define SPLIT 32
#define NIN 96
#define EPSV 1e-5f

typedef short short8 __attribute__((ext_vector_type(8)));
typedef float f32x4 __attribute__((ext_vector_type(4)));
typedef unsigned short u16;

// fp32 -> bf16 round-to-nearest-even (finite inputs)
__device__ __forceinline__ u16 f2bf(float f) {
    union { float f; unsigned int u; } c; c.f = f;
    unsigned int u = c.u + 0x7FFFu + ((c.u >> 16) & 1u);
    return (u16)(u >> 16);
}

__device__ __forceinline__ void gl_lds16(const u16* g, u16* l) {
    __builtin_amdgcn_global_load_lds(
        (const __attribute__((address_space(1))) unsigned int*)g,
        (__attribute__((address_space(3))) unsigned int*)l, 16, 0, 0);
}

// ds_read_b128 with compile-time immediate offset
#define DSRO(dst, addr, off) \
    asm volatile("ds_read_b128 %0, %1 offset:%2" : "=&v"(dst) : "v"(addr), "i"(off))

// ---------------------------------------------------------------------------
// Transpose + convert: dst[c][r] (bf16, row stride Rpad) = src[r][c] (f32)
// ---------------------------------------------------------------------------
__global__ void transpose_cvt_kernel(const float* __restrict__ src, u16* __restrict__ dst,
                                     int R, int C, int Rpad,
                                     long long sstride, long long dstride)
{
    __shared__ float tile[32][33];
    const float* s = src + (size_t)blockIdx.z * sstride;
    u16* d = dst + (size_t)blockIdx.z * dstride;
    int r0 = blockIdx.x * 32, c0 = blockIdx.y * 32;
    int tc = threadIdx.x & 31, tr = threadIdx.x >> 5;   // 32 x 8
#pragma unroll
    for (int i = 0; i < 4; ++i) {
        int r = r0 + tr + i * 8;
        tile[tr + i * 8][tc] = (r < R) ? s[(size_t)r * C + c0 + tc] : 0.f;
    }
    __syncthreads();
#pragma unroll
    for (int i = 0; i < 4; ++i) {
        int cc = tr + i * 8;
        d[(size_t)(c0 + cc) * Rpad + r0 + tc] = f2bf(tile[tc][cc]);
    }
}

// ---------------------------------------------------------------------------
// One-time: fill Ain cond columns (32..95) + zero pad (96..127), all BB rows.
// ---------------------------------------------------------------------------
__global__ __launch_bounds__(256)
void init_ain_cond_kernel(const float* __restrict__ cond, u16* __restrict__ Ain)
{
    int t = blockIdx.x * 256 + threadIdx.x;   // over BB*96
    int c = t % 96, r = t / 96;
    Ain[(size_t)r * 128 + 32 + c] = (c < CC) ? f2bf(cond[(size_t)r * CC + c]) : (u16)0;
}

// One-time (layer 0): fill Ain keep columns (0..31) from x.
__global__ __launch_bounds__(256)
void build_keep_kernel(const float* __restrict__ x, u16* __restrict__ Ain, int keep_off)
{
    int t = blockIdx.x * 256 + threadIdx.x;   // over BB*32
    int c = t & 31, r = t >> 5;
    Ain[(size_t)r * 128 + c] = f2bf(x[(size_t)r * DD + 2 * c + keep_off]);
}

// ---------------------------------------------------------------------------
// One K-tile (K=64) of compute: 16 ds_read_b128 (A frags) chained under
// 4x16 MFMA clusters via counted lgkmcnt(4) (DS completes in order).
// BASE selects the LDS buffer (0 or 32768) as a compile-time immediate.
// b0 = B frags for ksub0, b1 = ksub1 (already in registers; the compiler
// guards their first use with its own vmcnt wait).
// ---------------------------------------------------------------------------
template<int BASE>
__device__ __forceinline__ void k_tile(const unsigned lA, f32x4 (&acc)[8][4],
                                       const short8 (&b0)[4], const short8 (&b1)[4])
{
    short8 af[4], ag[4];
    DSRO(af[0], lA, BASE + 0);    DSRO(af[1], lA, BASE + 1024);
    DSRO(af[2], lA, BASE + 2048); DSRO(af[3], lA, BASE + 3072);
    DSRO(ag[0], lA, BASE + 4096); DSRO(ag[1], lA, BASE + 5120);
    DSRO(ag[2], lA, BASE + 6144); DSRO(ag[3], lA, BASE + 7168);
    asm volatile("s_waitcnt lgkmcnt(4)");       // af done (ag may be in flight)
    __builtin_amdgcn_sched_barrier(0);
    __builtin_amdgcn_s_setprio(1);
#pragma unroll
    for (int a = 0; a < 4; ++a)
#pragma unroll
        for (int b = 0; b < 4; ++b)
            acc[a][b] = __builtin_amdgcn_mfma_f32_16x16x32_bf16(af[a], b0[b], acc[a][b], 0, 0, 0);
    __builtin_amdgcn_s_setprio(0);
    DSRO(af[0], lA, BASE + 16384); DSRO(af[1], lA, BASE + 17408);
    DSRO(af[2], lA, BASE + 18432); DSRO(af[3], lA, BASE + 19456);
    asm volatile("s_waitcnt lgkmcnt(4)");       // ag done
    __builtin_amdgcn_sched_barrier(0);
    __builtin_amdgcn_s_setprio(1);
#pragma unroll
    for (int a = 0; a < 4; ++a)
#pragma unroll
        for (int b = 0; b < 4; ++b)
            acc[4 + a][b] = __builtin_amdgcn_mfma_f32_16x16x32_bf16(ag[a], b0[b], acc[4 + a][b], 0, 0, 0);
    __builtin_amdgcn_s_setprio(0);
    DSRO(ag[0], lA, BASE + 20480); DSRO(ag[1], lA, BASE + 21504);
    DSRO(ag[2], lA, BASE + 22528); DSRO(ag[3], lA, BASE + 23552);
    asm volatile("s_waitcnt lgkmcnt(4)");       // af (ksub1) done
    __builtin_amdgcn_sched_barrier(0);
    __builtin_amdgcn_s_setprio(1);
#pragma unroll
    for (int a = 0; a < 4; ++a)
#pragma unroll
        for (int b = 0; b < 4; ++b)
            acc[a][b] = __builtin_amdgcn_mfma_f32_16x16x32_bf16(af[a], b1[b], acc[a][b], 0, 0, 0);
    __builtin_amdgcn_s_setprio(0);
    asm volatile("s_waitcnt lgkmcnt(0)");       // ag (ksub1) done
    __builtin_amdgcn_sched_barrier(0);
    __builtin_amdgcn_s_setprio(1);
#pragma unroll
    for (int a = 0; a < 4; ++a)
#pragma unroll
        for (int b = 0; b < 4; ++b)
            acc[4 + a][b] = __builtin_amdgcn_mfma_f32_16x16x32_bf16(ag[a], b1[b], acc[4 + a][b], 0, 0, 0);
    __builtin_amdgcn_s_setprio(0);
}

// ---------------------------------------------------------------------------
// Tiled bf16 MFMA GEMM: C = relu(A @ Bt^T + bias), N = 1024 fixed.
// BM=256 x BN=256, 8 waves (2x4), wave tile 128x64 (acc 8x4).
// B never touches LDS: the B MFMA fragment equals the 16B/lane the old
// staging DMA fetched (identical per-lane global address), so a plain
// short8 load delivers it straight to registers (compiler emits
// global_load_dwordx4 + its own vmcnt guard before first use -> no manual
// VMEM accounting for B). B (weights, 2 MB) is L2-resident; the VMEM pipe
// runs parallel to LDS. LDS holds only A (2 x 32 KB double buffer).
// Per K-tile: 1 vmcnt(0) (staging-DMA guard) + 1 barrier, no intra-tile
// barriers -> waves skew and the ds_read / MFMA pipes overlap across waves;
// within a wave counted lgkmcnt(4) chains 4-read groups under 16-MFMA
// clusters. B registers double-buffered via the x2-unrolled tile loop.
// Requires K % 128 == 0; launches use K=128 / K=1024.
// ---------------------------------------------------------------------------
__global__ __launch_bounds__(512, 2)
void gemm_tiled(const u16* __restrict__ A,    // [M][K] bf16 row-major (chunk-local)
                const u16* __restrict__ Bt,   // [1024][K] bf16 N-major
                const float* __restrict__ bias,
                u16* __restrict__ Cc,         // [M][1024] bf16 out
                int K)
{
    __shared__ u16 sA[2][32 * 512];    // 64 KB: per buf 32 entries (ksub*16 + rowtile)

    const int t = threadIdx.x;
    const int w = t >> 6, lane = t & 63;
    const int lane16 = lane & 15, quad = lane >> 4;
    const int wm = w >> 2, wn = w & 3;          // 2 x 4 waves, wave tile 128x64

    // XCD swizzle: grid = nby x 4, col index fastest within an XCD
    int id = blockIdx.x;
    int nby = gridDim.x >> 2;
    int xcd = id & 7, slot = id >> 3;
    int bx = slot & 3, byq = slot >> 2;
    int by = xcd * (nby >> 3) + byq;
    const int bm = by * 256, bn = bx * 256;

    const int ntile = K >> 6;                  // BK=64 tiles (even)

    // stage one A K-tile (32 KB, 32 entries; 4 gl_lds per wave)
    auto stage_tile = [&](int kt2, int buf) {
        const u16* Abase = A + (size_t)(bm + lane16) * K + quad * 8 + (size_t)kt2 * 64;
#pragma unroll
        for (int r = 0; r < 4; ++r) {
            int e = r * 8 + w;
            int s = e >> 4, i = e & 15;
            const u16* g = Abase + (size_t)(i * 16) * K + s * 32;
            gl_lds16(g, &sA[buf][e * 512]);
        }
    };

    // load one K-tile of B fragments straight to registers (8 loads/wave)
    const u16* Bbase = Bt + (size_t)(bn + wn * 64 + lane16) * K + quad * 8;
    auto loadB = [&](int kt2, short8 (&b0)[4], short8 (&b1)[4]) {
#pragma unroll
        for (int j = 0; j < 4; ++j) {
            const u16* p = Bbase + (size_t)(j * 16) * K + (size_t)kt2 * 64;
            b0[j] = *(const short8*)p;
            b1[j] = *(const short8*)(p + 32);
        }
    };

    f32x4 acc[8][4];
#pragma unroll
    for (int a = 0; a < 8; ++a)
#pragma unroll
        for (int b = 0; b < 4; ++b) acc[a][b] = (f32x4){0.f, 0.f, 0.f, 0.f};

    const unsigned sAb = (unsigned)(size_t)(__attribute__((address_space(3))) u16*)&sA[0][0];
    const unsigned lA  = sAb + (unsigned)(wm * 8192 + lane * 16);

    short8 bA0[4], bA1[4], bB0[4], bB1[4];

    // ---- prologue: stage A(0) + load B(0) ----
    stage_tile(0, 0);
    loadB(0, bA0, bA1);
    asm volatile("s_waitcnt vmcnt(0)");
    __builtin_amdgcn_s_barrier();

    const int npair = ntile >> 1;
    for (int tp = 0; tp < npair; ++tp) {
        const int kt = tp << 1;
        // ---- even tile kt (buf0): prefetch kt+1 while computing ----
        loadB(kt + 1, bB0, bB1);
        stage_tile(kt + 1, 1);
        k_tile<0>(lA, acc, bA0, bA1);
        asm volatile("s_waitcnt vmcnt(0)");    // staging DMA (and B prefetch) landed
        __builtin_amdgcn_s_barrier();
        // ---- odd tile kt+1 (buf1): prefetch kt+2 while computing ----
        if (kt + 2 < ntile) {
            loadB(kt + 2, bA0, bA1);
            stage_tile(kt + 2, 0);
        }
        k_tile<32768>(lA, acc, bB0, bB1);
        asm volatile("s_waitcnt vmcnt(0)");
        __builtin_amdgcn_s_barrier();
    }
    __syncthreads();                           // LDS reusable

    // ---- epilogue: bias+relu+f2bf via per-wave scratch, coalesced stores ----
    constexpr int ES = 72;                     // shorts per scratch row
    float bv[4];
#pragma unroll
    for (int b = 0; b < 4; ++b) bv[b] = bias[bn + wn * 64 + b * 16 + lane16];
    u16* scr = ((u16*)sA) + w * (16 * ES);     // 2304 B per wave
#pragma unroll
    for (int a = 0; a < 8; ++a) {
#pragma unroll
        for (int b = 0; b < 4; ++b)
#pragma unroll
            for (int r = 0; r < 4; ++r) {
                float v = fmaxf(acc[a][b][r] + bv[b], 0.f);
                scr[(quad * 4 + r) * ES + b * 16 + lane16] = f2bf(v);
            }
#pragma unroll
        for (int ch = 0; ch < 2; ++ch) {
            int row = ch * 8 + (lane >> 3), colc = (lane & 7) * 8;
            short8 v = *(const short8*)(scr + row * ES + colc);
            *(short8*)(Cc + (size_t)(bm + wm * 128 + a * 16 + row) * 1024 + bn + wn * 64 + colc) = v;
        }
    }
}

// ---------------------------------------------------------------------------
// Fused GEMM3 + coupling. BM=128, 8 waves (4x2), wave tile 32x32.
// BK=64 DOUBLE-BUFFERED staging (one barrier per K-iter; this kernel runs at
// ~1 block/CU so exposed barriers were costly). st tile aliases the stage
// buffers after the final barrier.
// ---------------------------------------------------------------------------
__global__ __launch_bounds__(512)
void gemm3_coupling(const u16* __restrict__ A,    // h2 chunk [CH][1024]
                    const u16* __restrict__ Bt,   // wst [64][1024]
                    const float* __restrict__ bs, const float* __restrict__ bt,
                    float* __restrict__ x, float* __restrict__ log_det,
                    float* __restrict__ stat_sum, float* __restrict__ stat_sumsq,
                    int keep_off, int row0)
{
    constexpr int ST_STRIDE = 66;
    __shared__ u16 stg[2][24 * 512];                 // 48 KB (aliased by sst)
    __shared__ float ssum[8][64], ssum2[8][64];
    float* sst = (float*)stg;                        // 128*66*4 = 33.8 KB < 48 KB

    const int t = threadIdx.x;
    const int w = t >> 6, lane = t & 63;
    const int lane16 = lane & 15, quad = lane >> 4;
    const int wm = w >> 1, wn = w & 1;               // 4 x 2 waves
    const int bm = blockIdx.x * 128;

    // stage K-iter it: 24 entries (A: e=0..15 -> s=e>>3,i=e&7; B: 16..23)
    auto stage = [&](int it, int buf) {
        int k0 = it * 64;
#pragma unroll
        for (int p = 0; p < 3; ++p) {
            int e = w + p * 8;
            if (e < 16) {
                int s = e >> 3, i = e & 7;
                const u16* g = A + (size_t)(bm + i * 16 + lane16) * HH + (k0 + s * 32 + quad * 8);
                gl_lds16(g, &stg[buf][e * 512]);
            } else {
                int j2 = e - 16, s = j2 >> 2, j = j2 & 3;
                const u16* g = Bt + (size_t)(j * 16 + lane16) * HH + (k0 + s * 32 + quad * 8);
                gl_lds16(g, &stg[buf][e * 512]);
            }
        }
    };

    f32x4 acc[2][2];
#pragma unroll
    for (int a = 0; a < 2; ++a)
#pragma unroll
        for (int b = 0; b < 2; ++b) acc[a][b] = (f32x4){0.f, 0.f, 0.f, 0.f};

    stage(0, 0);
    for (int it = 0; it < 16; ++it) {
        const int buf = it & 1;
        __syncthreads();
        if (it + 1 < 16) stage(it + 1, buf ^ 1);
        u16* ldsA = stg[buf];
        u16* ldsB = stg[buf] + 16 * 512;
#pragma unroll
        for (int s = 0; s < 2; ++s) {
            short8 af[2], bfr[2];
#pragma unroll
            for (int a = 0; a < 2; ++a)
                af[a] = *(const short8*)(ldsA + ((s * 8 + wm * 2 + a) * 512) + lane * 8);
#pragma unroll
            for (int b = 0; b < 2; ++b)
                bfr[b] = *(const short8*)(ldsB + ((s * 4 + wn * 2 + b) * 512) + lane * 8);
#pragma unroll
            for (int a = 0; a < 2; ++a)
#pragma unroll
                for (int b = 0; b < 2; ++b)
                    acc[a][b] = __builtin_amdgcn_mfma_f32_16x16x32_bf16(af[a], bfr[b], acc[a][b], 0, 0, 0);
        }
    }
    __syncthreads();                                 // staging done; alias as sst

    // scatter acc -> LDS st tile (128 x 64)
#pragma unroll
    for (int a = 0; a < 2; ++a)
#pragma unroll
        for (int b = 0; b < 2; ++b)
#pragma unroll
            for (int r = 0; r < 4; ++r) {
                int row = wm * 32 + a * 16 + quad * 4 + r;
                int col = wn * 32 + b * 16 + lane16;
                sst[row * ST_STRIDE + col] = acc[a][b][r];
            }
    __syncthreads();

    // coupling: wave w -> rows [w*16, w*16+16), lane = feature f
    const int f = lane;
    const bool is_chg = ((f & 1) != keep_off);
    const int j = f >> 1;
    float bsj = 0.f, btj = 0.f;
    if (is_chg) { bsj = bs[j]; btj = bt[j]; }

    float lsum = 0.f, lsum2 = 0.f;
    for (int i = 0; i < 16; ++i) {
        int crow = w * 16 + i;
        int grow = row0 + bm + crow;
        float xv = x[(size_t)grow * DD + f];
        float ld = 0.f;
        if (is_chg) {
            float s_raw = sst[crow * ST_STRIDE + j];
            float t_raw = sst[crow * ST_STRIDE + SPLIT + j];
            float ls = tanhf(s_raw + bsj);
            float tv = t_raw + btj;
            xv = xv * expf(ls) + tv;
            x[(size_t)grow * DD + f] = xv;
            ld = ls;
        }
        for (int off = 32; off > 0; off >>= 1) ld += __shfl_down(ld, off, 64);
        if (f == 0) log_det[grow] += ld;
        lsum  += xv;
        lsum2 += xv * xv;
    }

    ssum[w][f]  = lsum;
    ssum2[w][f] = lsum2;
    __syncthreads();
    if (t < 64) {
        float a = 0.f, b = 0.f;
#pragma unroll
        for (int g = 0; g < 8; ++g) { a += ssum[g][t]; b += ssum2[g][t]; }
        atomicAdd(stat_sum + t, a);
        atomicAdd(stat_sumsq + t, b);
    }
}

// ---------------------------------------------------------------------------
// BN normalize (scale/shift computed in-block from raw stats); optionally
// writes bf16 keep-columns of next layer's Ain.
// ---------------------------------------------------------------------------
__global__ __launch_bounds__(256)
void normalize_kernel(const float* __restrict__ xin, float* __restrict__ xout,
                      const float* __restrict__ stat_sum, const float* __restrict__ stat_sumsq,
                      const float* __restrict__ bn_w, const float* __restrict__ bn_b,
                      float* __restrict__ log_det,
                      u16* __restrict__ Ain, int off_next)
{
    __shared__ float sscale[64], sshift[64], scsum;
    int t = threadIdx.x;
    if (t < 64) {
        const float invB = 1.f / (float)BB;
        float mean = stat_sum[t] * invB;
        float var  = stat_sumsq[t] * invB - mean * mean;
        float inv  = rsqrtf(var + EPSV);
        float wv   = bn_w[t];
        float sc   = inv * wv;
        sscale[t] = sc;
        sshift[t] = bn_b[t] - mean * sc;
        float lg = logf(fabsf(wv));
        for (int off = 32; off > 0; off >>= 1) lg += __shfl_down(lg, off, 64);
        if (t == 0) scsum = lg;
    }
    __syncthreads();

    int idx = blockIdx.x * blockDim.x + t;     // over B*64/4
    int f0 = (idx & 15) * 4;
    int row = idx >> 4;
    float4 v = ((const float4*)xin)[idx];
    v.x = v.x * sscale[f0 + 0] + sshift[f0 + 0];
    v.y = v.y * sscale[f0 + 1] + sshift[f0 + 1];
    v.z = v.z * sscale[f0 + 2] + sshift[f0 + 2];
    v.w = v.w * sscale[f0 + 3] + sshift[f0 + 3];
    ((float4*)xout)[idx] = v;
    if ((idx & 15) == 0) log_det[row] += scsum;
    if (Ain) {
        float a0 = off_next ? v.y : v.x;
        float a1 = off_next ? v.w : v.z;
        ushort2 u; u.x = f2bf(a0); u.y = f2bf(a1);
        *(ushort2*)(Ain + (size_t)row * 128 + (f0 >> 1)) = u;
    }
}

// ---------------------------------------------------------------------------
extern "C" void kernel_launch(void* const* d_in, const int* in_sizes, int n_in,
                              void* d_out, int out_size, void* d_ws, size_t ws_size,
                              hipStream_t stream)
{
    const float* z    = (const float*)d_in[0];
    const float* cond = (const float*)d_in[1];
    const float* W1   = (const float*)d_in[2];
    const float* b1   = (const float*)d_in[3];
    const float* W2   = (const float*)d_in[4];
    const float* b2   = (const float*)d_in[5];
    const float* Ws   = (const float*)d_in[6];
    const float* bs   = (const float*)d_in[7];
    const float* Wt   = (const float*)d_in[8];
    const float* bt   = (const float*)d_in[9];
    const float* bn_w = (const float*)d_in[10];
    const float* bn_b = (const float*)d_in[11];

    float* out_x  = (float*)d_out;
    float* out_ld = out_x + (size_t)BB * DD;

    // ---- workspace: fixed part ~30.5 MB + h1/h2 (CH*4 KB) ----
    char* p = (char*)d_ws;
    size_t used = 0;
    auto alloc = [&](size_t bytes) { void* q = p + used; used += (bytes + 255) & ~(size_t)255; return q; };

    float* xbuf = (float*)alloc((size_t)BB * DD * 4);
    u16*   w1t  = (u16*)alloc((size_t)LL * HH * 128 * 2);
    u16*   w2t  = (u16*)alloc((size_t)LL * HH * HH * 2);
    u16*   wstt = (u16*)alloc((size_t)LL * 64 * HH * 2);
    u16*   Ain  = (u16*)alloc((size_t)BB * 128 * 2);
    float* stat_sum   = (float*)alloc(64 * 4);
    float* stat_sumsq = (float*)alloc(64 * 4);

    int CH = BB;
    while (CH > 8192 && used + (size_t)CH * 4096 + 4096 > ws_size) CH >>= 1;
    u16* h1 = (u16*)alloc((size_t)CH * HH * 2);
    u16* h2 = (u16*)alloc((size_t)CH * HH * 2);

    // ---- init ----
    hipMemcpyAsync(xbuf, z, (size_t)BB * DD * sizeof(float), hipMemcpyDeviceToDevice, stream);
    hipMemsetAsync(out_ld, 0, (size_t)BB * sizeof(float), stream);

    transpose_cvt_kernel<<<dim3(128/32, HH/32, LL), 256, 0, stream>>>(
        W1, w1t, NIN, HH, 128, (long long)NIN * HH, (long long)HH * 128);
    transpose_cvt_kernel<<<dim3(HH/32, HH/32, LL), 256, 0, stream>>>(
        W2, w2t, HH, HH, HH, (long long)HH * HH, (long long)HH * HH);
    transpose_cvt_kernel<<<dim3(HH/32, SPLIT/32, LL), 256, 0, stream>>>(
        Ws, wstt, HH, SPLIT, HH, (long long)HH * SPLIT, (long long)64 * HH);
    transpose_cvt_kernel<<<dim3(HH/32, SPLIT/32, LL), 256, 0, stream>>>(
        Wt, wstt + (size_t)SPLIT * HH, HH, SPLIT, HH, (long long)HH * SPLIT, (long long)64 * HH);

    init_ain_cond_kernel<<<BB * 96 / 256, 256, 0, stream>>>(cond, Ain);
    build_keep_kernel<<<BB * 32 / 256, 256, 0, stream>>>(xbuf, Ain, 0);

    for (int l = 0; l < LL; ++l) {
        const int off = l & 1;
        hipMemsetAsync(stat_sum, 0, 2 * 64 * sizeof(float), stream);

        for (int c = 0; c < BB / CH; ++c) {
            const int row0 = c * CH;

            // GEMM1: h1 = relu(Ain @ W1t^T + b1)   M=CH, K=128
            gemm_tiled<<<(CH / 256) * 4, 512, 0, stream>>>(
                Ain + (size_t)row0 * 128, w1t + (size_t)l * HH * 128,
                b1 + (size_t)l * HH, h1, 128);

            // GEMM2: h2 = relu(h1 @ W2t^T + b2)    M=CH, K=1024
            gemm_tiled<<<(CH / 256) * 4, 512, 0, stream>>>(
                h1, w2t + (size_t)l * HH * HH,
                b2 + (size_t)l * HH, h2, HH);

            // GEMM3 + coupling fused (BM=128, double-buffered)
            gemm3_coupling<<<CH / 128, 512, 0, stream>>>(
                h2, wstt + (size_t)l * 64 * HH,
                bs + (size_t)l * SPLIT, bt + (size_t)l * SPLIT,
                xbuf, out_ld, stat_sum, stat_sumsq, off, row0);
        }

        float* xout = (l == LL - 1) ? out_x : xbuf;
        u16* ain_next = (l < LL - 1) ? Ain : nullptr;
        normalize_kernel<<<(BB * DD / 4) / 256, 256, 0, stream>>>(
            xbuf, xout, stat_sum, stat_sumsq,
            bn_w + (size_t)l * DD, bn_b + (size_t)l * DD,
            out_ld, ain_next, (l + 1) & 1);
    }
}

// Round 7
// 1269.311 us; speedup vs baseline: 1.3772x; 1.3772x over previous
//
#include <hip/hip_runtime.h>
#include <math.h>

// Problem constants
#define BB 32768
#define DD 64
#define CC 64
#define HH 1024
#define LL 6
#define SPLIT 32
#define NIN 96
#define EPSV 1e-5f

typedef short short8 __attribute__((ext_vector_type(8)));
typedef float f32x4 __attribute__((ext_vector_type(4)));
typedef unsigned short u16;

// fp32 -> bf16 round-to-nearest-even (finite inputs)
__device__ __forceinline__ u16 f2bf(float f) {
    union { float f; unsigned int u; } c; c.f = f;
    unsigned int u = c.u + 0x7FFFu + ((c.u >> 16) & 1u);
    return (u16)(u >> 16);
}

__device__ __forceinline__ void gl_lds16(const u16* g, u16* l) {
    __builtin_amdgcn_global_load_lds(
        (const __attribute__((address_space(1))) unsigned int*)g,
        (__attribute__((address_space(3))) unsigned int*)l, 16, 0, 0);
}

// ds_read_b128 with compile-time immediate offset
#define DSRO(dst, addr, off) \
    asm volatile("ds_read_b128 %0, %1 offset:%2" : "=&v"(dst) : "v"(addr), "i"(off))

// ---------------------------------------------------------------------------
// Transpose + convert: dst[c][r] (bf16, row stride Rpad) = src[r][c] (f32)
// ---------------------------------------------------------------------------
__global__ void transpose_cvt_kernel(const float* __restrict__ src, u16* __restrict__ dst,
                                     int R, int C, int Rpad,
                                     long long sstride, long long dstride)
{
    __shared__ float tile[32][33];
    const float* s = src + (size_t)blockIdx.z * sstride;
    u16* d = dst + (size_t)blockIdx.z * dstride;
    int r0 = blockIdx.x * 32, c0 = blockIdx.y * 32;
    int tc = threadIdx.x & 31, tr = threadIdx.x >> 5;   // 32 x 8
#pragma unroll
    for (int i = 0; i < 4; ++i) {
        int r = r0 + tr + i * 8;
        tile[tr + i * 8][tc] = (r < R) ? s[(size_t)r * C + c0 + tc] : 0.f;
    }
    __syncthreads();
#pragma unroll
    for (int i = 0; i < 4; ++i) {
        int cc = tr + i * 8;
        d[(size_t)(c0 + cc) * Rpad + r0 + tc] = f2bf(tile[tc][cc]);
    }
}

// ---------------------------------------------------------------------------
// One-time: fill Ain cond columns (32..95) + zero pad (96..127), all BB rows.
// ---------------------------------------------------------------------------
__global__ __launch_bounds__(256)
void init_ain_cond_kernel(const float* __restrict__ cond, u16* __restrict__ Ain)
{
    int t = blockIdx.x * 256 + threadIdx.x;   // over BB*96
    int c = t % 96, r = t / 96;
    Ain[(size_t)r * 128 + 32 + c] = (c < CC) ? f2bf(cond[(size_t)r * CC + c]) : (u16)0;
}

// One-time (layer 0): fill Ain keep columns (0..31) from x.
__global__ __launch_bounds__(256)
void build_keep_kernel(const float* __restrict__ x, u16* __restrict__ Ain, int keep_off)
{
    int t = blockIdx.x * 256 + threadIdx.x;   // over BB*32
    int c = t & 31, r = t >> 5;
    Ain[(size_t)r * 128 + c] = f2bf(x[(size_t)r * DD + 2 * c + keep_off]);
}

// ---------------------------------------------------------------------------
// One K-tile (K=64): 16 ds_read_b128 (A frags) chained under 4x16 MFMA
// clusters via counted lgkmcnt (DS completes in order). lAc = per-tile LDS
// base (buffer parity folded into the address register; offsets stay
// immediate). b0/b1 = this tile's B fragments (loaded by plain C++ global
// loads; compiler guards first use with its own vmcnt).
// ---------------------------------------------------------------------------
__device__ __forceinline__ void k_tile(const unsigned lAc, f32x4 (&acc)[8][4],
                                       const short8 (&b0)[4], const short8 (&b1)[4])
{
    short8 af[4], ag[4];
    DSRO(af[0], lAc, 0);    DSRO(af[1], lAc, 1024);
    DSRO(af[2], lAc, 2048); DSRO(af[3], lAc, 3072);
    DSRO(ag[0], lAc, 4096); DSRO(ag[1], lAc, 5120);
    DSRO(ag[2], lAc, 6144); DSRO(ag[3], lAc, 7168);
    asm volatile("s_waitcnt lgkmcnt(4)");       // af done (ag may be in flight)
    __builtin_amdgcn_sched_barrier(0);
    __builtin_amdgcn_s_setprio(1);
#pragma unroll
    for (int a = 0; a < 4; ++a)
#pragma unroll
        for (int b = 0; b < 4; ++b)
            acc[a][b] = __builtin_amdgcn_mfma_f32_16x16x32_bf16(af[a], b0[b], acc[a][b], 0, 0, 0);
    __builtin_amdgcn_s_setprio(0);
    DSRO(af[0], lAc, 16384); DSRO(af[1], lAc, 17408);
    DSRO(af[2], lAc, 18432); DSRO(af[3], lAc, 19456);
    asm volatile("s_waitcnt lgkmcnt(4)");       // ag done
    __builtin_amdgcn_sched_barrier(0);
    __builtin_amdgcn_s_setprio(1);
#pragma unroll
    for (int a = 0; a < 4; ++a)
#pragma unroll
        for (int b = 0; b < 4; ++b)
            acc[4 + a][b] = __builtin_amdgcn_mfma_f32_16x16x32_bf16(ag[a], b0[b], acc[4 + a][b], 0, 0, 0);
    __builtin_amdgcn_s_setprio(0);
    DSRO(ag[0], lAc, 20480); DSRO(ag[1], lAc, 21504);
    DSRO(ag[2], lAc, 22528); DSRO(ag[3], lAc, 23552);
    asm volatile("s_waitcnt lgkmcnt(4)");       // af (ksub1) done
    __builtin_amdgcn_sched_barrier(0);
    __builtin_amdgcn_s_setprio(1);
#pragma unroll
    for (int a = 0; a < 4; ++a)
#pragma unroll
        for (int b = 0; b < 4; ++b)
            acc[a][b] = __builtin_amdgcn_mfma_f32_16x16x32_bf16(af[a], b1[b], acc[a][b], 0, 0, 0);
    __builtin_amdgcn_s_setprio(0);
    asm volatile("s_waitcnt lgkmcnt(0)");       // ag (ksub1) done
    __builtin_amdgcn_sched_barrier(0);
    __builtin_amdgcn_s_setprio(1);
#pragma unroll
    for (int a = 0; a < 4; ++a)
#pragma unroll
        for (int b = 0; b < 4; ++b)
            acc[4 + a][b] = __builtin_amdgcn_mfma_f32_16x16x32_bf16(ag[a], b1[b], acc[4 + a][b], 0, 0, 0);
    __builtin_amdgcn_s_setprio(0);
}

// ---------------------------------------------------------------------------
// Tiled bf16 MFMA GEMM: C = relu(A @ Bt^T + bias), N = 1024 fixed.
// BM=256 x BN=256, 8 waves (2x4), wave tile 128x64 (acc 8x4).
// B never touches LDS (fragment == the 16B/lane the old staging DMA
// fetched). NO cross-tile B register buffer (round-6 spill fix): b0/b1
// (32 VGPR) are loaded per tile via plain short8 derefs; B (2 MB weights)
// is L2-resident, ~200-300cy exposed once per ~2500cy tile, covered by
// wave skew. LDS holds only A (2 x 32 KB double buffer), DMA-staged one
// tile ahead. ONE vmcnt(0)+s_barrier per K-tile (DMA had a full tile to
// land), no intra-tile barriers -> waves skew freely and the ds_read /
// MFMA pipes overlap across waves. Peak live regs ~220 < 256.
// Requires K % 64 == 0, ntile >= 2; launches use K=128 / K=1024.
// ---------------------------------------------------------------------------
__global__ __launch_bounds__(512, 2)
void gemm_tiled(const u16* __restrict__ A,    // [M][K] bf16 row-major (chunk-local)
                const u16* __restrict__ Bt,   // [1024][K] bf16 N-major
                const float* __restrict__ bias,
                u16* __restrict__ Cc,         // [M][1024] bf16 out
                int K)
{
    __shared__ u16 sA[2][32 * 512];    // 64 KB: per buf 32 entries (ksub*16 + rowtile)

    const int t = threadIdx.x;
    const int w = t >> 6, lane = t & 63;
    const int lane16 = lane & 15, quad = lane >> 4;
    const int wm = w >> 2, wn = w & 3;          // 2 x 4 waves, wave tile 128x64

    // XCD swizzle: grid = nby x 4, col index fastest within an XCD
    int id = blockIdx.x;
    int nby = gridDim.x >> 2;
    int xcd = id & 7, slot = id >> 3;
    int bx = slot & 3, byq = slot >> 2;
    int by = xcd * (nby >> 3) + byq;
    const int bm = by * 256, bn = bx * 256;

    const int ntile = K >> 6;                  // BK=64 tiles

    // stage one A K-tile (32 KB, 32 entries; 4 gl_lds per wave)
    auto stage_tile = [&](int kt2, int buf) {
        const u16* Abase = A + (size_t)(bm + lane16) * K + quad * 8 + (size_t)kt2 * 64;
#pragma unroll
        for (int r = 0; r < 4; ++r) {
            int e = r * 8 + w;
            int s = e >> 4, i = e & 15;
            const u16* g = Abase + (size_t)(i * 16) * K + s * 32;
            gl_lds16(g, &sA[buf][e * 512]);
        }
    };

    // load this tile's B fragments straight to registers (8 loads/wave)
    const u16* Bbase = Bt + (size_t)(bn + wn * 64 + lane16) * K + quad * 8;
    auto loadB = [&](int kt2, short8 (&b0)[4], short8 (&b1)[4]) {
#pragma unroll
        for (int j = 0; j < 4; ++j) {
            const u16* p = Bbase + (size_t)(j * 16) * K + (size_t)kt2 * 64;
            b0[j] = *(const short8*)p;
            b1[j] = *(const short8*)(p + 32);
        }
    };

    f32x4 acc[8][4];
#pragma unroll
    for (int a = 0; a < 8; ++a)
#pragma unroll
        for (int b = 0; b < 4; ++b) acc[a][b] = (f32x4){0.f, 0.f, 0.f, 0.f};

    const unsigned sAb = (unsigned)(size_t)(__attribute__((address_space(3))) u16*)&sA[0][0];
    const unsigned lA  = sAb + (unsigned)(wm * 8192 + lane * 16);

    // ---- prologue: stage A(0) ----
    stage_tile(0, 0);
    asm volatile("s_waitcnt vmcnt(0)");
    __builtin_amdgcn_s_barrier();

    for (int kt = 0; kt < ntile; ++kt) {
        short8 b0[4], b1[4];
        loadB(kt, b0, b1);                     // this tile's B -> regs
        if (kt + 1 < ntile) stage_tile(kt + 1, (kt + 1) & 1);
        const unsigned lAc = lA + (unsigned)((kt & 1) << 15);
        k_tile(lAc, acc, b0, b1);
        asm volatile("s_waitcnt vmcnt(0)");    // next-tile DMA landed (had full tile)
        __builtin_amdgcn_s_barrier();
    }
    __syncthreads();                           // LDS reusable

    // ---- epilogue: bias+relu+f2bf via per-wave scratch, coalesced stores ----
    constexpr int ES = 72;                     // shorts per scratch row
    float bv[4];
#pragma unroll
    for (int b = 0; b < 4; ++b) bv[b] = bias[bn + wn * 64 + b * 16 + lane16];
    u16* scr = ((u16*)sA) + w * (16 * ES);     // 2304 B per wave
#pragma unroll
    for (int a = 0; a < 8; ++a) {
#pragma unroll
        for (int b = 0; b < 4; ++b)
#pragma unroll
            for (int r = 0; r < 4; ++r) {
                float v = fmaxf(acc[a][b][r] + bv[b], 0.f);
                scr[(quad * 4 + r) * ES + b * 16 + lane16] = f2bf(v);
            }
#pragma unroll
        for (int ch = 0; ch < 2; ++ch) {
            int row = ch * 8 + (lane >> 3), colc = (lane & 7) * 8;
            short8 v = *(const short8*)(scr + row * ES + colc);
            *(short8*)(Cc + (size_t)(bm + wm * 128 + a * 16 + row) * 1024 + bn + wn * 64 + colc) = v;
        }
    }
}

// ---------------------------------------------------------------------------
// Fused GEMM3 + coupling. BM=128, 8 waves (4x2), wave tile 32x32.
// BK=64 DOUBLE-BUFFERED staging (one barrier per K-iter; this kernel runs at
// ~1 block/CU so exposed barriers were costly). st tile aliases the stage
// buffers after the final barrier.
// ---------------------------------------------------------------------------
__global__ __launch_bounds__(512)
void gemm3_coupling(const u16* __restrict__ A,    // h2 chunk [CH][1024]
                    const u16* __restrict__ Bt,   // wst [64][1024]
                    const float* __restrict__ bs, const float* __restrict__ bt,
                    float* __restrict__ x, float* __restrict__ log_det,
                    float* __restrict__ stat_sum, float* __restrict__ stat_sumsq,
                    int keep_off, int row0)
{
    constexpr int ST_STRIDE = 66;
    __shared__ u16 stg[2][24 * 512];                 // 48 KB (aliased by sst)
    __shared__ float ssum[8][64], ssum2[8][64];
    float* sst = (float*)stg;                        // 128*66*4 = 33.8 KB < 48 KB

    const int t = threadIdx.x;
    const int w = t >> 6, lane = t & 63;
    const int lane16 = lane & 15, quad = lane >> 4;
    const int wm = w >> 1, wn = w & 1;               // 4 x 2 waves
    const int bm = blockIdx.x * 128;

    // stage K-iter it: 24 entries (A: e=0..15 -> s=e>>3,i=e&7; B: 16..23)
    auto stage = [&](int it, int buf) {
        int k0 = it * 64;
#pragma unroll
        for (int p = 0; p < 3; ++p) {
            int e = w + p * 8;
            if (e < 16) {
                int s = e >> 3, i = e & 7;
                const u16* g = A + (size_t)(bm + i * 16 + lane16) * HH + (k0 + s * 32 + quad * 8);
                gl_lds16(g, &stg[buf][e * 512]);
            } else {
                int j2 = e - 16, s = j2 >> 2, j = j2 & 3;
                const u16* g = Bt + (size_t)(j * 16 + lane16) * HH + (k0 + s * 32 + quad * 8);
                gl_lds16(g, &stg[buf][e * 512]);
            }
        }
    };

    f32x4 acc[2][2];
#pragma unroll
    for (int a = 0; a < 2; ++a)
#pragma unroll
        for (int b = 0; b < 2; ++b) acc[a][b] = (f32x4){0.f, 0.f, 0.f, 0.f};

    stage(0, 0);
    for (int it = 0; it < 16; ++it) {
        const int buf = it & 1;
        __syncthreads();
        if (it + 1 < 16) stage(it + 1, buf ^ 1);
        u16* ldsA = stg[buf];
        u16* ldsB = stg[buf] + 16 * 512;
#pragma unroll
        for (int s = 0; s < 2; ++s) {
            short8 af[2], bfr[2];
#pragma unroll
            for (int a = 0; a < 2; ++a)
                af[a] = *(const short8*)(ldsA + ((s * 8 + wm * 2 + a) * 512) + lane * 8);
#pragma unroll
            for (int b = 0; b < 2; ++b)
                bfr[b] = *(const short8*)(ldsB + ((s * 4 + wn * 2 + b) * 512) + lane * 8);
#pragma unroll
            for (int a = 0; a < 2; ++a)
#pragma unroll
                for (int b = 0; b < 2; ++b)
                    acc[a][b] = __builtin_amdgcn_mfma_f32_16x16x32_bf16(af[a], bfr[b], acc[a][b], 0, 0, 0);
        }
    }
    __syncthreads();                                 // staging done; alias as sst

    // scatter acc -> LDS st tile (128 x 64)
#pragma unroll
    for (int a = 0; a < 2; ++a)
#pragma unroll
        for (int b = 0; b < 2; ++b)
#pragma unroll
            for (int r = 0; r < 4; ++r) {
                int row = wm * 32 + a * 16 + quad * 4 + r;
                int col = wn * 32 + b * 16 + lane16;
                sst[row * ST_STRIDE + col] = acc[a][b][r];
            }
    __syncthreads();

    // coupling: wave w -> rows [w*16, w*16+16), lane = feature f
    const int f = lane;
    const bool is_chg = ((f & 1) != keep_off);
    const int j = f >> 1;
    float bsj = 0.f, btj = 0.f;
    if (is_chg) { bsj = bs[j]; btj = bt[j]; }

    float lsum = 0.f, lsum2 = 0.f;
    for (int i = 0; i < 16; ++i) {
        int crow = w * 16 + i;
        int grow = row0 + bm + crow;
        float xv = x[(size_t)grow * DD + f];
        float ld = 0.f;
        if (is_chg) {
            float s_raw = sst[crow * ST_STRIDE + j];
            float t_raw = sst[crow * ST_STRIDE + SPLIT + j];
            float ls = tanhf(s_raw + bsj);
            float tv = t_raw + btj;
            xv = xv * expf(ls) + tv;
            x[(size_t)grow * DD + f] = xv;
            ld = ls;
        }
        for (int off = 32; off > 0; off >>= 1) ld += __shfl_down(ld, off, 64);
        if (f == 0) log_det[grow] += ld;
        lsum  += xv;
        lsum2 += xv * xv;
    }

    ssum[w][f]  = lsum;
    ssum2[w][f] = lsum2;
    __syncthreads();
    if (t < 64) {
        float a = 0.f, b = 0.f;
#pragma unroll
        for (int g = 0; g < 8; ++g) { a += ssum[g][t]; b += ssum2[g][t]; }
        atomicAdd(stat_sum + t, a);
        atomicAdd(stat_sumsq + t, b);
    }
}

// ---------------------------------------------------------------------------
// BN normalize (scale/shift computed in-block from raw stats); optionally
// writes bf16 keep-columns of next layer's Ain.
// ---------------------------------------------------------------------------
__global__ __launch_bounds__(256)
void normalize_kernel(const float* __restrict__ xin, float* __restrict__ xout,
                      const float* __restrict__ stat_sum, const float* __restrict__ stat_sumsq,
                      const float* __restrict__ bn_w, const float* __restrict__ bn_b,
                      float* __restrict__ log_det,
                      u16* __restrict__ Ain, int off_next)
{
    __shared__ float sscale[64], sshift[64], scsum;
    int t = threadIdx.x;
    if (t < 64) {
        const float invB = 1.f / (float)BB;
        float mean = stat_sum[t] * invB;
        float var  = stat_sumsq[t] * invB - mean * mean;
        float inv  = rsqrtf(var + EPSV);
        float wv   = bn_w[t];
        float sc   = inv * wv;
        sscale[t] = sc;
        sshift[t] = bn_b[t] - mean * sc;
        float lg = logf(fabsf(wv));
        for (int off = 32; off > 0; off >>= 1) lg += __shfl_down(lg, off, 64);
        if (t == 0) scsum = lg;
    }
    __syncthreads();

    int idx = blockIdx.x * blockDim.x + t;     // over B*64/4
    int f0 = (idx & 15) * 4;
    int row = idx >> 4;
    float4 v = ((const float4*)xin)[idx];
    v.x = v.x * sscale[f0 + 0] + sshift[f0 + 0];
    v.y = v.y * sscale[f0 + 1] + sshift[f0 + 1];
    v.z = v.z * sscale[f0 + 2] + sshift[f0 + 2];
    v.w = v.w * sscale[f0 + 3] + sshift[f0 + 3];
    ((float4*)xout)[idx] = v;
    if ((idx & 15) == 0) log_det[row] += scsum;
    if (Ain) {
        float a0 = off_next ? v.y : v.x;
        float a1 = off_next ? v.w : v.z;
        ushort2 u; u.x = f2bf(a0); u.y = f2bf(a1);
        *(ushort2*)(Ain + (size_t)row * 128 + (f0 >> 1)) = u;
    }
}

// ---------------------------------------------------------------------------
extern "C" void kernel_launch(void* const* d_in, const int* in_sizes, int n_in,
                              void* d_out, int out_size, void* d_ws, size_t ws_size,
                              hipStream_t stream)
{
    const float* z    = (const float*)d_in[0];
    const float* cond = (const float*)d_in[1];
    const float* W1   = (const float*)d_in[2];
    const float* b1   = (const float*)d_in[3];
    const float* W2   = (const float*)d_in[4];
    const float* b2   = (const float*)d_in[5];
    const float* Ws   = (const float*)d_in[6];
    const float* bs   = (const float*)d_in[7];
    const float* Wt   = (const float*)d_in[8];
    const float* bt   = (const float*)d_in[9];
    const float* bn_w = (const float*)d_in[10];
    const float* bn_b = (const float*)d_in[11];

    float* out_x  = (float*)d_out;
    float* out_ld = out_x + (size_t)BB * DD;

    // ---- workspace: fixed part ~30.5 MB + h1/h2 (CH*4 KB) ----
    char* p = (char*)d_ws;
    size_t used = 0;
    auto alloc = [&](size_t bytes) { void* q = p + used; used += (bytes + 255) & ~(size_t)255; return q; };

    float* xbuf = (float*)alloc((size_t)BB * DD * 4);
    u16*   w1t  = (u16*)alloc((size_t)LL * HH * 128 * 2);
    u16*   w2t  = (u16*)alloc((size_t)LL * HH * HH * 2);
    u16*   wstt = (u16*)alloc((size_t)LL * 64 * HH * 2);
    u16*   Ain  = (u16*)alloc((size_t)BB * 128 * 2);
    float* stat_sum   = (float*)alloc(64 * 4);
    float* stat_sumsq = (float*)alloc(64 * 4);

    int CH = BB;
    while (CH > 8192 && used + (size_t)CH * 4096 + 4096 > ws_size) CH >>= 1;
    u16* h1 = (u16*)alloc((size_t)CH * HH * 2);
    u16* h2 = (u16*)alloc((size_t)CH * HH * 2);

    // ---- init ----
    hipMemcpyAsync(xbuf, z, (size_t)BB * DD * sizeof(float), hipMemcpyDeviceToDevice, stream);
    hipMemsetAsync(out_ld, 0, (size_t)BB * sizeof(float), stream);

    transpose_cvt_kernel<<<dim3(128/32, HH/32, LL), 256, 0, stream>>>(
        W1, w1t, NIN, HH, 128, (long long)NIN * HH, (long long)HH * 128);
    transpose_cvt_kernel<<<dim3(HH/32, HH/32, LL), 256, 0, stream>>>(
        W2, w2t, HH, HH, HH, (long long)HH * HH, (long long)HH * HH);
    transpose_cvt_kernel<<<dim3(HH/32, SPLIT/32, LL), 256, 0, stream>>>(
        Ws, wstt, HH, SPLIT, HH, (long long)HH * SPLIT, (long long)64 * HH);
    transpose_cvt_kernel<<<dim3(HH/32, SPLIT/32, LL), 256, 0, stream>>>(
        Wt, wstt + (size_t)SPLIT * HH, HH, SPLIT, HH, (long long)HH * SPLIT, (long long)64 * HH);

    init_ain_cond_kernel<<<BB * 96 / 256, 256, 0, stream>>>(cond, Ain);
    build_keep_kernel<<<BB * 32 / 256, 256, 0, stream>>>(xbuf, Ain, 0);

    for (int l = 0; l < LL; ++l) {
        const int off = l & 1;
        hipMemsetAsync(stat_sum, 0, 2 * 64 * sizeof(float), stream);

        for (int c = 0; c < BB / CH; ++c) {
            const int row0 = c * CH;

            // GEMM1: h1 = relu(Ain @ W1t^T + b1)   M=CH, K=128
            gemm_tiled<<<(CH / 256) * 4, 512, 0, stream>>>(
                Ain + (size_t)row0 * 128, w1t + (size_t)l * HH * 128,
                b1 + (size_t)l * HH, h1, 128);

            // GEMM2: h2 = relu(h1 @ W2t^T + b2)    M=CH, K=1024
            gemm_tiled<<<(CH / 256) * 4, 512, 0, stream>>>(
                h1, w2t + (size_t)l * HH * HH,
                b2 + (size_t)l * HH, h2, HH);

            // GEMM3 + coupling fused (BM=128, double-buffered)
            gemm3_coupling<<<CH / 128, 512, 0, stream>>>(
                h2, wstt + (size_t)l * 64 * HH,
                bs + (size_t)l * SPLIT, bt + (size_t)l * SPLIT,
                xbuf, out_ld, stat_sum, stat_sumsq, off, row0);
        }

        float* xout = (l == LL - 1) ? out_x : xbuf;
        u16* ain_next = (l < LL - 1) ? Ain : nullptr;
        normalize_kernel<<<(BB * DD / 4) / 256, 256, 0, stream>>>(
            xbuf, xout, stat_sum, stat_sumsq,
            bn_w + (size_t)l * DD, bn_b + (size_t)l * DD,
            out_ld, ain_next, (l + 1) & 1);
    }
}

// Round 8
// 1158.575 us; speedup vs baseline: 1.5089x; 1.0956x over previous
//
#include <hip/hip_runtime.h>
#include <math.h>

// Problem constants
#define BB 32768
#define DD 64
#define CC 64
#define HH 1024
#define LL 6
#define SPLIT 32
#define NIN 96
#define EPSV 1e-5f

typedef short short8 __attribute__((ext_vector_type(8)));
typedef float f32x4 __attribute__((ext_vector_type(4)));
typedef unsigned short u16;

// fp32 -> bf16 round-to-nearest-even (finite inputs)
__device__ __forceinline__ u16 f2bf(float f) {
    union { float f; unsigned int u; } c; c.f = f;
    unsigned int u = c.u + 0x7FFFu + ((c.u >> 16) & 1u);
    return (u16)(u >> 16);
}

__device__ __forceinline__ void gl_lds16(const u16* g, u16* l) {
    __builtin_amdgcn_global_load_lds(
        (const __attribute__((address_space(1))) unsigned int*)g,
        (__attribute__((address_space(3))) unsigned int*)l, 16, 0, 0);
}

#define DSR(dst, addr, off) \
    asm volatile("ds_read_b128 %0, %1 offset:" #off : "=&v"(dst) : "v"(addr))

// ---------------------------------------------------------------------------
// Transpose + convert: dst[c][r] (bf16, row stride Rpad) = src[r][c] (f32)
// ---------------------------------------------------------------------------
__global__ void transpose_cvt_kernel(const float* __restrict__ src, u16* __restrict__ dst,
                                     int R, int C, int Rpad,
                                     long long sstride, long long dstride)
{
    __shared__ float tile[32][33];
    const float* s = src + (size_t)blockIdx.z * sstride;
    u16* d = dst + (size_t)blockIdx.z * dstride;
    int r0 = blockIdx.x * 32, c0 = blockIdx.y * 32;
    int tc = threadIdx.x & 31, tr = threadIdx.x >> 5;   // 32 x 8
#pragma unroll
    for (int i = 0; i < 4; ++i) {
        int r = r0 + tr + i * 8;
        tile[tr + i * 8][tc] = (r < R) ? s[(size_t)r * C + c0 + tc] : 0.f;
    }
    __syncthreads();
#pragma unroll
    for (int i = 0; i < 4; ++i) {
        int cc = tr + i * 8;
        d[(size_t)(c0 + cc) * Rpad + r0 + tc] = f2bf(tile[tc][cc]);
    }
}

// ---------------------------------------------------------------------------
// One-time: fill Ain cond columns (32..95) + zero pad (96..127), all BB rows.
// ---------------------------------------------------------------------------
__global__ __launch_bounds__(256)
void init_ain_cond_kernel(const float* __restrict__ cond, u16* __restrict__ Ain)
{
    int t = blockIdx.x * 256 + threadIdx.x;   // over BB*96
    int c = t % 96, r = t / 96;
    Ain[(size_t)r * 128 + 32 + c] = (c < CC) ? f2bf(cond[(size_t)r * CC + c]) : (u16)0;
}

// One-time (layer 0): fill Ain keep columns (0..31) from x.
__global__ __launch_bounds__(256)
void build_keep_kernel(const float* __restrict__ x, u16* __restrict__ Ain, int keep_off)
{
    int t = blockIdx.x * 256 + threadIdx.x;   // over BB*32
    int c = t & 31, r = t >> 5;
    Ain[(size_t)r * 128 + c] = f2bf(x[(size_t)r * DD + 2 * c + keep_off]);
}

// ---------------------------------------------------------------------------
// Tiled bf16 MFMA GEMM: C = relu(A @ Bt^T + bias), N = 1024 fixed.
// BM=256 x BN=256, 8 waves (2x4), wave tile 128x64 (acc 8x4).
// Round-4 structure (best measured: 83 us @ M=32768): m201-style phases,
// BK=64 K-tiles, 2-deep double-buffered LDS (128 KB, 1 block/CU),
// entry-contiguous layout. 4 phases per K-tile:
//   {4-8 ds_read_b128 ; stage 1 half-tile (2 gl_lds) ; s_barrier ;
//    lgkmcnt(0) ; sched_barrier(0) ; setprio(1) ; 16 MFMA ; setprio(0) ;
//    [vmcnt(4) at ph1/ph3] ; s_barrier}
// With CH=16384 the staged A (h1 chunk, 32 MB) is L2-resident, so the
// guarded vmcnt(4) drains are covered by the 2-3 phase staging distance.
// Works for any K multiple of 64 (ntile>=1); launches use K=128 / K=1024.
// ---------------------------------------------------------------------------
__global__ __launch_bounds__(512, 2)
void gemm_tiled(const u16* __restrict__ A,    // [M][K] bf16 row-major (chunk-local)
                const u16* __restrict__ Bt,   // [1024][K] bf16 N-major
                const float* __restrict__ bias,
                u16* __restrict__ Cc,         // [M][1024] bf16 out
                int K)
{
    __shared__ u16 sA[2][32 * 512];    // 64 KB: per buf 32 entries (ksub*16 + rowtile)
    __shared__ u16 sB[2][32 * 512];    // 64 KB: per buf 32 entries (ksub*16 + coltile)

    const int t = threadIdx.x;
    const int w = t >> 6, lane = t & 63;
    const int lane16 = lane & 15, quad = lane >> 4;
    const int wm = w >> 2, wn = w & 3;          // 2 x 4 waves, wave tile 128x64

    // XCD swizzle: grid = nby x 4, col index fastest within an XCD
    int id = blockIdx.x;
    int nby = gridDim.x >> 2;
    int xcd = id & 7, slot = id >> 3;
    int bx = slot & 3, byq = slot >> 2;
    int by = xcd * (nby >> 3) + byq;
    const int bm = by * 256, bn = bx * 256;

    const int ntile = K >> 6;                  // BK=64 tiles

    // stage one half-tile (16 entries = 16 KB; 2 gl_lds per wave)
    // op: 0=A, 1=B; s: ksub (0/1); buf: destination parity
    auto stage_half = [&](int kt, int op, int s, int buf) {
        int k0 = kt * 64 + s * 32 + quad * 8;
#pragma unroll
        for (int r = 0; r < 2; ++r) {
            int i = r * 8 + w;
            int e = s * 16 + i;
            if (op == 0) {
                const u16* g = A + (size_t)(bm + i * 16 + lane16) * K + k0;
                gl_lds16(g, &sA[buf][e * 512]);
            } else {
                const u16* g = Bt + (size_t)(bn + i * 16 + lane16) * K + k0;
                gl_lds16(g, &sB[buf][e * 512]);
            }
        }
    };

    f32x4 acc[8][4];
#pragma unroll
    for (int a = 0; a < 8; ++a)
#pragma unroll
        for (int b = 0; b < 4; ++b) acc[a][b] = (f32x4){0.f, 0.f, 0.f, 0.f};

    // LDS byte addresses (as3 ptrtoint = group-segment offset)
    const unsigned sAb = (unsigned)(size_t)(__attribute__((address_space(3))) u16*)&sA[0][0];
    const unsigned sBb = (unsigned)(size_t)(__attribute__((address_space(3))) u16*)&sB[0][0];
    const unsigned aoff = (unsigned)(wm * 8 * 1024 + lane * 16);   // wm*8 entries
    const unsigned boff = (unsigned)(wn * 4 * 1024 + lane * 16);   // wn*4 entries

    // ---- prologue: stage tile 0 (4 half-tiles, 8 loads/wave) ----
    stage_half(0, 0, 0, 0);
    stage_half(0, 1, 0, 0);
    stage_half(0, 0, 1, 0);
    stage_half(0, 1, 1, 0);
    asm volatile("s_waitcnt vmcnt(4)");        // ksub0 halves landed
    __builtin_amdgcn_s_barrier();

    short8 af[4], ag[4], bf[4], bg[4];
    for (int kt = 0; kt < ntile; ++kt) {
        const unsigned base = (unsigned)((kt & 1) << 15);       // *32768 B
        const unsigned aA0 = sAb + base + aoff;
        const unsigned aB0 = sBb + base + boff;
        const unsigned aA1 = aA0 + 16384;
        const unsigned aB1 = aB0 + 16384;
        const int nk = (kt + 1 < ntile) ? kt + 1 : kt;          // dummy on last
        const int nb = (kt + 1) & 1;

        // ================= phase 0: (a0-3) x b x k0 =================
        DSR(bf[0], aB0, 0); DSR(bf[1], aB0, 1024);
        DSR(bf[2], aB0, 2048); DSR(bf[3], aB0, 3072);
        DSR(af[0], aA0, 0); DSR(af[1], aA0, 1024);
        DSR(af[2], aA0, 2048); DSR(af[3], aA0, 3072);
        stage_half(nk, 0, 0, nb);              // H(kt+1, A, ks0)
        __builtin_amdgcn_s_barrier();
        asm volatile("s_waitcnt lgkmcnt(0)");
        __builtin_amdgcn_sched_barrier(0);
        __builtin_amdgcn_s_setprio(1);
#pragma unroll
        for (int a = 0; a < 4; ++a)
#pragma unroll
            for (int b = 0; b < 4; ++b)
                acc[a][b] = __builtin_amdgcn_mfma_f32_16x16x32_bf16(af[a], bf[b], acc[a][b], 0, 0, 0);
        __builtin_amdgcn_s_setprio(0);
        __builtin_amdgcn_s_barrier();

        // ================= phase 1: (a4-7) x b x k0 =================
        DSR(ag[0], aA0, 4096); DSR(ag[1], aA0, 5120);
        DSR(ag[2], aA0, 6144); DSR(ag[3], aA0, 7168);
        stage_half(nk, 1, 0, nb);              // H(kt+1, B, ks0)
        __builtin_amdgcn_s_barrier();
        asm volatile("s_waitcnt lgkmcnt(0)");
        __builtin_amdgcn_sched_barrier(0);
        __builtin_amdgcn_s_setprio(1);
#pragma unroll
        for (int a = 0; a < 4; ++a)
#pragma unroll
            for (int b = 0; b < 4; ++b)
                acc[4 + a][b] = __builtin_amdgcn_mfma_f32_16x16x32_bf16(ag[a], bf[b], acc[4 + a][b], 0, 0, 0);
        __builtin_amdgcn_s_setprio(0);
        asm volatile("s_waitcnt vmcnt(4)");    // this tile's ksub1 halves landed
        __builtin_amdgcn_s_barrier();

        // ================= phase 2: (a0-3) x b x k1 =================
        DSR(bg[0], aB1, 0); DSR(bg[1], aB1, 1024);
        DSR(bg[2], aB1, 2048); DSR(bg[3], aB1, 3072);
        DSR(af[0], aA1, 0); DSR(af[1], aA1, 1024);
        DSR(af[2], aA1, 2048); DSR(af[3], aA1, 3072);
        stage_half(nk, 0, 1, nb);              // H(kt+1, A, ks1)
        __builtin_amdgcn_s_barrier();
        asm volatile("s_waitcnt lgkmcnt(0)");
        __builtin_amdgcn_sched_barrier(0);
        __builtin_amdgcn_s_setprio(1);
#pragma unroll
        for (int a = 0; a < 4; ++a)
#pragma unroll
            for (int b = 0; b < 4; ++b)
                acc[a][b] = __builtin_amdgcn_mfma_f32_16x16x32_bf16(af[a], bg[b], acc[a][b], 0, 0, 0);
        __builtin_amdgcn_s_setprio(0);
        __builtin_amdgcn_s_barrier();

        // ================= phase 3: (a4-7) x b x k1 =================
        DSR(ag[0], aA1, 4096); DSR(ag[1], aA1, 5120);
        DSR(ag[2], aA1, 6144); DSR(ag[3], aA1, 7168);
        stage_half(nk, 1, 1, nb);              // H(kt+1, B, ks1)
        __builtin_amdgcn_s_barrier();
        asm volatile("s_waitcnt lgkmcnt(0)");
        __builtin_amdgcn_sched_barrier(0);
        __builtin_amdgcn_s_setprio(1);
#pragma unroll
        for (int a = 0; a < 4; ++a)
#pragma unroll
            for (int b = 0; b < 4; ++b)
                acc[4 + a][b] = __builtin_amdgcn_mfma_f32_16x16x32_bf16(ag[a], bg[b], acc[4 + a][b], 0, 0, 0);
        __builtin_amdgcn_s_setprio(0);
        asm volatile("s_waitcnt vmcnt(4)");    // next tile's ksub0 halves landed
        __builtin_amdgcn_s_barrier();
    }
    __syncthreads();                           // drains DMA (incl. dummy); LDS reusable

    // ---- epilogue: bias+relu+f2bf via per-wave scratch, coalesced stores ----
    constexpr int ES = 72;                     // shorts per scratch row
    float bv[4];
#pragma unroll
    for (int b = 0; b < 4; ++b) bv[b] = bias[bn + wn * 64 + b * 16 + lane16];
    u16* scr = ((u16*)sB) + w * (16 * ES);     // 2304 B per wave
#pragma unroll
    for (int a = 0; a < 8; ++a) {
#pragma unroll
        for (int b = 0; b < 4; ++b)
#pragma unroll
            for (int r = 0; r < 4; ++r) {
                float v = fmaxf(acc[a][b][r] + bv[b], 0.f);
                scr[(quad * 4 + r) * ES + b * 16 + lane16] = f2bf(v);
            }
#pragma unroll
        for (int ch = 0; ch < 2; ++ch) {
            int row = ch * 8 + (lane >> 3), colc = (lane & 7) * 8;
            short8 v = *(const short8*)(scr + row * ES + colc);
            *(short8*)(Cc + (size_t)(bm + wm * 128 + a * 16 + row) * 1024 + bn + wn * 64 + colc) = v;
        }
    }
}

// ---------------------------------------------------------------------------
// Fused GEMM3 + coupling. BM=128, 8 waves (4x2), wave tile 32x32.
// BK=64 DOUBLE-BUFFERED staging (one barrier per K-iter; this kernel runs at
// ~1 block/CU so exposed barriers were costly). st tile aliases the stage
// buffers after the final barrier.
// ---------------------------------------------------------------------------
__global__ __launch_bounds__(512)
void gemm3_coupling(const u16* __restrict__ A,    // h2 chunk [CH][1024]
                    const u16* __restrict__ Bt,   // wst [64][1024]
                    const float* __restrict__ bs, const float* __restrict__ bt,
                    float* __restrict__ x, float* __restrict__ log_det,
                    float* __restrict__ stat_sum, float* __restrict__ stat_sumsq,
                    int keep_off, int row0)
{
    constexpr int ST_STRIDE = 66;
    __shared__ u16 stg[2][24 * 512];                 // 48 KB (aliased by sst)
    __shared__ float ssum[8][64], ssum2[8][64];
    float* sst = (float*)stg;                        // 128*66*4 = 33.8 KB < 48 KB

    const int t = threadIdx.x;
    const int w = t >> 6, lane = t & 63;
    const int lane16 = lane & 15, quad = lane >> 4;
    const int wm = w >> 1, wn = w & 1;               // 4 x 2 waves
    const int bm = blockIdx.x * 128;

    // stage K-iter it: 24 entries (A: e=0..15 -> s=e>>3,i=e&7; B: 16..23)
    auto stage = [&](int it, int buf) {
        int k0 = it * 64;
#pragma unroll
        for (int p = 0; p < 3; ++p) {
            int e = w + p * 8;
            if (e < 16) {
                int s = e >> 3, i = e & 7;
                const u16* g = A + (size_t)(bm + i * 16 + lane16) * HH + (k0 + s * 32 + quad * 8);
                gl_lds16(g, &stg[buf][e * 512]);
            } else {
                int j2 = e - 16, s = j2 >> 2, j = j2 & 3;
                const u16* g = Bt + (size_t)(j * 16 + lane16) * HH + (k0 + s * 32 + quad * 8);
                gl_lds16(g, &stg[buf][e * 512]);
            }
        }
    };

    f32x4 acc[2][2];
#pragma unroll
    for (int a = 0; a < 2; ++a)
#pragma unroll
        for (int b = 0; b < 2; ++b) acc[a][b] = (f32x4){0.f, 0.f, 0.f, 0.f};

    stage(0, 0);
    for (int it = 0; it < 16; ++it) {
        const int buf = it & 1;
        __syncthreads();
        if (it + 1 < 16) stage(it + 1, buf ^ 1);
        u16* ldsA = stg[buf];
        u16* ldsB = stg[buf] + 16 * 512;
#pragma unroll
        for (int s = 0; s < 2; ++s) {
            short8 af[2], bfr[2];
#pragma unroll
            for (int a = 0; a < 2; ++a)
                af[a] = *(const short8*)(ldsA + ((s * 8 + wm * 2 + a) * 512) + lane * 8);
#pragma unroll
            for (int b = 0; b < 2; ++b)
                bfr[b] = *(const short8*)(ldsB + ((s * 4 + wn * 2 + b) * 512) + lane * 8);
#pragma unroll
            for (int a = 0; a < 2; ++a)
#pragma unroll
                for (int b = 0; b < 2; ++b)
                    acc[a][b] = __builtin_amdgcn_mfma_f32_16x16x32_bf16(af[a], bfr[b], acc[a][b], 0, 0, 0);
        }
    }
    __syncthreads();                                 // staging done; alias as sst

    // scatter acc -> LDS st tile (128 x 64)
#pragma unroll
    for (int a = 0; a < 2; ++a)
#pragma unroll
        for (int b = 0; b < 2; ++b)
#pragma unroll
            for (int r = 0; r < 4; ++r) {
                int row = wm * 32 + a * 16 + quad * 4 + r;
                int col = wn * 32 + b * 16 + lane16;
                sst[row * ST_STRIDE + col] = acc[a][b][r];
            }
    __syncthreads();

    // coupling: wave w -> rows [w*16, w*16+16), lane = feature f
    const int f = lane;
    const bool is_chg = ((f & 1) != keep_off);
    const int j = f >> 1;
    float bsj = 0.f, btj = 0.f;
    if (is_chg) { bsj = bs[j]; btj = bt[j]; }

    float lsum = 0.f, lsum2 = 0.f;
    for (int i = 0; i < 16; ++i) {
        int crow = w * 16 + i;
        int grow = row0 + bm + crow;
        float xv = x[(size_t)grow * DD + f];
        float ld = 0.f;
        if (is_chg) {
            float s_raw = sst[crow * ST_STRIDE + j];
            float t_raw = sst[crow * ST_STRIDE + SPLIT + j];
            float ls = tanhf(s_raw + bsj);
            float tv = t_raw + btj;
            xv = xv * expf(ls) + tv;
            x[(size_t)grow * DD + f] = xv;
            ld = ls;
        }
        for (int off = 32; off > 0; off >>= 1) ld += __shfl_down(ld, off, 64);
        if (f == 0) log_det[grow] += ld;
        lsum  += xv;
        lsum2 += xv * xv;
    }

    ssum[w][f]  = lsum;
    ssum2[w][f] = lsum2;
    __syncthreads();
    if (t < 64) {
        float a = 0.f, b = 0.f;
#pragma unroll
        for (int g = 0; g < 8; ++g) { a += ssum[g][t]; b += ssum2[g][t]; }
        atomicAdd(stat_sum + t, a);
        atomicAdd(stat_sumsq + t, b);
    }
}

// ---------------------------------------------------------------------------
// BN normalize (scale/shift computed in-block from raw stats); optionally
// writes bf16 keep-columns of next layer's Ain.
// ---------------------------------------------------------------------------
__global__ __launch_bounds__(256)
void normalize_kernel(const float* __restrict__ xin, float* __restrict__ xout,
                      const float* __restrict__ stat_sum, const float* __restrict__ stat_sumsq,
                      const float* __restrict__ bn_w, const float* __restrict__ bn_b,
                      float* __restrict__ log_det,
                      u16* __restrict__ Ain, int off_next)
{
    __shared__ float sscale[64], sshift[64], scsum;
    int t = threadIdx.x;
    if (t < 64) {
        const float invB = 1.f / (float)BB;
        float mean = stat_sum[t] * invB;
        float var  = stat_sumsq[t] * invB - mean * mean;
        float inv  = rsqrtf(var + EPSV);
        float wv   = bn_w[t];
        float sc   = inv * wv;
        sscale[t] = sc;
        sshift[t] = bn_b[t] - mean * sc;
        float lg = logf(fabsf(wv));
        for (int off = 32; off > 0; off >>= 1) lg += __shfl_down(lg, off, 64);
        if (t == 0) scsum = lg;
    }
    __syncthreads();

    int idx = blockIdx.x * blockDim.x + t;     // over B*64/4
    int f0 = (idx & 15) * 4;
    int row = idx >> 4;
    float4 v = ((const float4*)xin)[idx];
    v.x = v.x * sscale[f0 + 0] + sshift[f0 + 0];
    v.y = v.y * sscale[f0 + 1] + sshift[f0 + 1];
    v.z = v.z * sscale[f0 + 2] + sshift[f0 + 2];
    v.w = v.w * sscale[f0 + 3] + sshift[f0 + 3];
    ((float4*)xout)[idx] = v;
    if ((idx & 15) == 0) log_det[row] += scsum;
    if (Ain) {
        float a0 = off_next ? v.y : v.x;
        float a1 = off_next ? v.w : v.z;
        ushort2 u; u.x = f2bf(a0); u.y = f2bf(a1);
        *(ushort2*)(Ain + (size_t)row * 128 + (f0 >> 1)) = u;
    }
}

// ---------------------------------------------------------------------------
extern "C" void kernel_launch(void* const* d_in, const int* in_sizes, int n_in,
                              void* d_out, int out_size, void* d_ws, size_t ws_size,
                              hipStream_t stream)
{
    const float* z    = (const float*)d_in[0];
    const float* cond = (const float*)d_in[1];
    const float* W1   = (const float*)d_in[2];
    const float* b1   = (const float*)d_in[3];
    const float* W2   = (const float*)d_in[4];
    const float* b2   = (const float*)d_in[5];
    const float* Ws   = (const float*)d_in[6];
    const float* bs   = (const float*)d_in[7];
    const float* Wt   = (const float*)d_in[8];
    const float* bt   = (const float*)d_in[9];
    const float* bn_w = (const float*)d_in[10];
    const float* bn_b = (const float*)d_in[11];

    float* out_x  = (float*)d_out;
    float* out_ld = out_x + (size_t)BB * DD;

    // ---- workspace: fixed part ~30.5 MB + h1/h2 (CH*4 KB) ----
    char* p = (char*)d_ws;
    size_t used = 0;
    auto alloc = [&](size_t bytes) { void* q = p + used; used += (bytes + 255) & ~(size_t)255; return q; };

    float* xbuf = (float*)alloc((size_t)BB * DD * 4);
    u16*   w1t  = (u16*)alloc((size_t)LL * HH * 128 * 2);
    u16*   w2t  = (u16*)alloc((size_t)LL * HH * HH * 2);
    u16*   wstt = (u16*)alloc((size_t)LL * 64 * HH * 2);
    u16*   Ain  = (u16*)alloc((size_t)BB * 128 * 2);
    float* stat_sum   = (float*)alloc(64 * 4);
    float* stat_sumsq = (float*)alloc(64 * 4);

    // CH=16384: h1/h2 = 32 MB each -> GEMM2's A (h1) and GEMM3's A (h2) are
    // L2/L3-warm from the producing kernel; grids stay exactly 256 blocks
    // (1/CU) for GEMM1/GEMM2. Fallback halves CH if workspace is short.
    int CH = 16384;
    while (CH > 4096 && used + (size_t)CH * 4096 + 4096 > ws_size) CH >>= 1;
    u16* h1 = (u16*)alloc((size_t)CH * HH * 2);
    u16* h2 = (u16*)alloc((size_t)CH * HH * 2);

    // ---- init ----
    hipMemcpyAsync(xbuf, z, (size_t)BB * DD * sizeof(float), hipMemcpyDeviceToDevice, stream);
    hipMemsetAsync(out_ld, 0, (size_t)BB * sizeof(float), stream);

    transpose_cvt_kernel<<<dim3(128/32, HH/32, LL), 256, 0, stream>>>(
        W1, w1t, NIN, HH, 128, (long long)NIN * HH, (long long)HH * 128);
    transpose_cvt_kernel<<<dim3(HH/32, HH/32, LL), 256, 0, stream>>>(
        W2, w2t, HH, HH, HH, (long long)HH * HH, (long long)HH * HH);
    transpose_cvt_kernel<<<dim3(HH/32, SPLIT/32, LL), 256, 0, stream>>>(
        Ws, wstt, HH, SPLIT, HH, (long long)HH * SPLIT, (long long)64 * HH);
    transpose_cvt_kernel<<<dim3(HH/32, SPLIT/32, LL), 256, 0, stream>>>(
        Wt, wstt + (size_t)SPLIT * HH, HH, SPLIT, HH, (long long)HH * SPLIT, (long long)64 * HH);

    init_ain_cond_kernel<<<BB * 96 / 256, 256, 0, stream>>>(cond, Ain);
    build_keep_kernel<<<BB * 32 / 256, 256, 0, stream>>>(xbuf, Ain, 0);

    for (int l = 0; l < LL; ++l) {
        const int off = l & 1;
        hipMemsetAsync(stat_sum, 0, 2 * 64 * sizeof(float), stream);

        for (int c = 0; c < BB / CH; ++c) {
            const int row0 = c * CH;

            // GEMM1: h1 = relu(Ain @ W1t^T + b1)   M=CH, K=128
            gemm_tiled<<<(CH / 256) * 4, 512, 0, stream>>>(
                Ain + (size_t)row0 * 128, w1t + (size_t)l * HH * 128,
                b1 + (size_t)l * HH, h1, 128);

            // GEMM2: h2 = relu(h1 @ W2t^T + b2)    M=CH, K=1024
            gemm_tiled<<<(CH / 256) * 4, 512, 0, stream>>>(
                h1, w2t + (size_t)l * HH * HH,
                b2 + (size_t)l * HH, h2, HH);

            // GEMM3 + coupling fused (BM=128, double-buffered)
            gemm3_coupling<<<CH / 128, 512, 0, stream>>>(
                h2, wstt + (size_t)l * 64 * HH,
                bs + (size_t)l * SPLIT, bt + (size_t)l * SPLIT,
                xbuf, out_ld, stat_sum, stat_sumsq, off, row0);
        }

        float* xout = (l == LL - 1) ? out_x : xbuf;
        u16* ain_next = (l < LL - 1) ? Ain : nullptr;
        normalize_kernel<<<(BB * DD / 4) / 256, 256, 0, stream>>>(
            xbuf, xout, stat_sum, stat_sumsq,
            bn_w + (size_t)l * DD, bn_b + (size_t)l * DD,
            out_ld, ain_next, (l + 1) & 1);
    }
}

// Round 9
// 944.971 us; speedup vs baseline: 1.8499x; 1.2260x over previous
//
#include <hip/hip_runtime.h>
#include <math.h>

// Problem constants
#define BB 32768
#define DD 64
#define CC 64
#define HH 1024
#define LL 6
#define SPLIT 32
#define NIN 96
#define EPSV 1e-5f

typedef short short8 __attribute__((ext_vector_type(8)));
typedef float f32x4 __attribute__((ext_vector_type(4)));
typedef unsigned short u16;

// fp32 -> bf16 round-to-nearest-even (finite inputs)
__device__ __forceinline__ u16 f2bf(float f) {
    union { float f; unsigned int u; } c; c.f = f;
    unsigned int u = c.u + 0x7FFFu + ((c.u >> 16) & 1u);
    return (u16)(u >> 16);
}

__device__ __forceinline__ void gl_lds16(const u16* g, u16* l) {
    __builtin_amdgcn_global_load_lds(
        (const __attribute__((address_space(1))) unsigned int*)g,
        (__attribute__((address_space(3))) unsigned int*)l, 16, 0, 0);
}

#define DSR(dst, addr, off) \
    asm volatile("ds_read_b128 %0, %1 offset:" #off : "=&v"(dst) : "v"(addr))

// ---------------------------------------------------------------------------
// Transpose + convert: dst[c][r] (bf16, row stride Rpad) = src[r][c] (f32)
// ---------------------------------------------------------------------------
__global__ void transpose_cvt_kernel(const float* __restrict__ src, u16* __restrict__ dst,
                                     int R, int C, int Rpad,
                                     long long sstride, long long dstride)
{
    __shared__ float tile[32][33];
    const float* s = src + (size_t)blockIdx.z * sstride;
    u16* d = dst + (size_t)blockIdx.z * dstride;
    int r0 = blockIdx.x * 32, c0 = blockIdx.y * 32;
    int tc = threadIdx.x & 31, tr = threadIdx.x >> 5;   // 32 x 8
#pragma unroll
    for (int i = 0; i < 4; ++i) {
        int r = r0 + tr + i * 8;
        tile[tr + i * 8][tc] = (r < R) ? s[(size_t)r * C + c0 + tc] : 0.f;
    }
    __syncthreads();
#pragma unroll
    for (int i = 0; i < 4; ++i) {
        int cc = tr + i * 8;
        d[(size_t)(c0 + cc) * Rpad + r0 + tc] = f2bf(tile[tc][cc]);
    }
}

// ---------------------------------------------------------------------------
// One-time: fill Ain cond columns (32..95) + zero pad (96..127), all BB rows.
// ---------------------------------------------------------------------------
__global__ __launch_bounds__(256)
void init_ain_cond_kernel(const float* __restrict__ cond, u16* __restrict__ Ain)
{
    int t = blockIdx.x * 256 + threadIdx.x;   // over BB*96
    int c = t % 96, r = t / 96;
    Ain[(size_t)r * 128 + 32 + c] = (c < CC) ? f2bf(cond[(size_t)r * CC + c]) : (u16)0;
}

// One-time (layer 0): fill Ain keep columns (0..31) from x.
__global__ __launch_bounds__(256)
void build_keep_kernel(const float* __restrict__ x, u16* __restrict__ Ain, int keep_off)
{
    int t = blockIdx.x * 256 + threadIdx.x;   // over BB*32
    int c = t & 31, r = t >> 5;
    Ain[(size_t)r * 128 + c] = f2bf(x[(size_t)r * DD + 2 * c + keep_off]);
}

// ---------------------------------------------------------------------------
// Tiled bf16 MFMA GEMM: C = relu(A @ Bt^T + bias), N = 1024 fixed.
// BM=256 x BN=256, 8 waves (2x4), wave tile 128x64 (acc 8x4).
// FROZEN at the round-4 structure (best measured: 83 us @ M=32768):
// m201-style phases, BK=64 K-tiles, 2-deep double-buffered LDS (128 KB,
// 1 block/CU), entry-contiguous layout (conflict-free per counters).
// 4 phases per K-tile:
//   {4-8 ds_read_b128 ; stage 1 half-tile (2 gl_lds) ; s_barrier ;
//    lgkmcnt(0) ; sched_barrier(0) ; setprio(1) ; 16 MFMA ; setprio(0) ;
//    [vmcnt(4) at ph1/ph3] ; s_barrier}
// Works for any K multiple of 64 (ntile>=1); launches use K=128 / K=1024.
// ---------------------------------------------------------------------------
__global__ __launch_bounds__(512, 2)
void gemm_tiled(const u16* __restrict__ A,    // [M][K] bf16 row-major (chunk-local)
                const u16* __restrict__ Bt,   // [1024][K] bf16 N-major
                const float* __restrict__ bias,
                u16* __restrict__ Cc,         // [M][1024] bf16 out
                int K)
{
    __shared__ u16 sA[2][32 * 512];    // 64 KB: per buf 32 entries (ksub*16 + rowtile)
    __shared__ u16 sB[2][32 * 512];    // 64 KB: per buf 32 entries (ksub*16 + coltile)

    const int t = threadIdx.x;
    const int w = t >> 6, lane = t & 63;
    const int lane16 = lane & 15, quad = lane >> 4;
    const int wm = w >> 2, wn = w & 3;          // 2 x 4 waves, wave tile 128x64

    // XCD swizzle: grid = nby x 4, col index fastest within an XCD
    int id = blockIdx.x;
    int nby = gridDim.x >> 2;
    int xcd = id & 7, slot = id >> 3;
    int bx = slot & 3, byq = slot >> 2;
    int by = xcd * (nby >> 3) + byq;
    const int bm = by * 256, bn = bx * 256;

    const int ntile = K >> 6;                  // BK=64 tiles

    // stage one half-tile (16 entries = 16 KB; 2 gl_lds per wave)
    // op: 0=A, 1=B; s: ksub (0/1); buf: destination parity
    auto stage_half = [&](int kt, int op, int s, int buf) {
        int k0 = kt * 64 + s * 32 + quad * 8;
#pragma unroll
        for (int r = 0; r < 2; ++r) {
            int i = r * 8 + w;
            int e = s * 16 + i;
            if (op == 0) {
                const u16* g = A + (size_t)(bm + i * 16 + lane16) * K + k0;
                gl_lds16(g, &sA[buf][e * 512]);
            } else {
                const u16* g = Bt + (size_t)(bn + i * 16 + lane16) * K + k0;
                gl_lds16(g, &sB[buf][e * 512]);
            }
        }
    };

    f32x4 acc[8][4];
#pragma unroll
    for (int a = 0; a < 8; ++a)
#pragma unroll
        for (int b = 0; b < 4; ++b) acc[a][b] = (f32x4){0.f, 0.f, 0.f, 0.f};

    // LDS byte addresses (as3 ptrtoint = group-segment offset)
    const unsigned sAb = (unsigned)(size_t)(__attribute__((address_space(3))) u16*)&sA[0][0];
    const unsigned sBb = (unsigned)(size_t)(__attribute__((address_space(3))) u16*)&sB[0][0];
    const unsigned aoff = (unsigned)(wm * 8 * 1024 + lane * 16);   // wm*8 entries
    const unsigned boff = (unsigned)(wn * 4 * 1024 + lane * 16);   // wn*4 entries

    // ---- prologue: stage tile 0 (4 half-tiles, 8 loads/wave) ----
    stage_half(0, 0, 0, 0);
    stage_half(0, 1, 0, 0);
    stage_half(0, 0, 1, 0);
    stage_half(0, 1, 1, 0);
    asm volatile("s_waitcnt vmcnt(4)");        // ksub0 halves landed
    __builtin_amdgcn_s_barrier();

    short8 af[4], ag[4], bf[4], bg[4];
    for (int kt = 0; kt < ntile; ++kt) {
        const unsigned base = (unsigned)((kt & 1) << 15);       // *32768 B
        const unsigned aA0 = sAb + base + aoff;
        const unsigned aB0 = sBb + base + boff;
        const unsigned aA1 = aA0 + 16384;
        const unsigned aB1 = aB0 + 16384;
        const int nk = (kt + 1 < ntile) ? kt + 1 : kt;          // dummy on last
        const int nb = (kt + 1) & 1;

        // ================= phase 0: (a0-3) x b x k0 =================
        DSR(bf[0], aB0, 0); DSR(bf[1], aB0, 1024);
        DSR(bf[2], aB0, 2048); DSR(bf[3], aB0, 3072);
        DSR(af[0], aA0, 0); DSR(af[1], aA0, 1024);
        DSR(af[2], aA0, 2048); DSR(af[3], aA0, 3072);
        stage_half(nk, 0, 0, nb);              // H(kt+1, A, ks0)
        __builtin_amdgcn_s_barrier();
        asm volatile("s_waitcnt lgkmcnt(0)");
        __builtin_amdgcn_sched_barrier(0);
        __builtin_amdgcn_s_setprio(1);
#pragma unroll
        for (int a = 0; a < 4; ++a)
#pragma unroll
            for (int b = 0; b < 4; ++b)
                acc[a][b] = __builtin_amdgcn_mfma_f32_16x16x32_bf16(af[a], bf[b], acc[a][b], 0, 0, 0);
        __builtin_amdgcn_s_setprio(0);
        __builtin_amdgcn_s_barrier();

        // ================= phase 1: (a4-7) x b x k0 =================
        DSR(ag[0], aA0, 4096); DSR(ag[1], aA0, 5120);
        DSR(ag[2], aA0, 6144); DSR(ag[3], aA0, 7168);
        stage_half(nk, 1, 0, nb);              // H(kt+1, B, ks0)
        __builtin_amdgcn_s_barrier();
        asm volatile("s_waitcnt lgkmcnt(0)");
        __builtin_amdgcn_sched_barrier(0);
        __builtin_amdgcn_s_setprio(1);
#pragma unroll
        for (int a = 0; a < 4; ++a)
#pragma unroll
            for (int b = 0; b < 4; ++b)
                acc[4 + a][b] = __builtin_amdgcn_mfma_f32_16x16x32_bf16(ag[a], bf[b], acc[4 + a][b], 0, 0, 0);
        __builtin_amdgcn_s_setprio(0);
        asm volatile("s_waitcnt vmcnt(4)");    // this tile's ksub1 halves landed
        __builtin_amdgcn_s_barrier();

        // ================= phase 2: (a0-3) x b x k1 =================
        DSR(bg[0], aB1, 0); DSR(bg[1], aB1, 1024);
        DSR(bg[2], aB1, 2048); DSR(bg[3], aB1, 3072);
        DSR(af[0], aA1, 0); DSR(af[1], aA1, 1024);
        DSR(af[2], aA1, 2048); DSR(af[3], aA1, 3072);
        stage_half(nk, 0, 1, nb);              // H(kt+1, A, ks1)
        __builtin_amdgcn_s_barrier();
        asm volatile("s_waitcnt lgkmcnt(0)");
        __builtin_amdgcn_sched_barrier(0);
        __builtin_amdgcn_s_setprio(1);
#pragma unroll
        for (int a = 0; a < 4; ++a)
#pragma unroll
            for (int b = 0; b < 4; ++b)
                acc[a][b] = __builtin_amdgcn_mfma_f32_16x16x32_bf16(af[a], bg[b], acc[a][b], 0, 0, 0);
        __builtin_amdgcn_s_setprio(0);
        __builtin_amdgcn_s_barrier();

        // ================= phase 3: (a4-7) x b x k1 =================
        DSR(ag[0], aA1, 4096); DSR(ag[1], aA1, 5120);
        DSR(ag[2], aA1, 6144); DSR(ag[3], aA1, 7168);
        stage_half(nk, 1, 1, nb);              // H(kt+1, B, ks1)
        __builtin_amdgcn_s_barrier();
        asm volatile("s_waitcnt lgkmcnt(0)");
        __builtin_amdgcn_sched_barrier(0);
        __builtin_amdgcn_s_setprio(1);
#pragma unroll
        for (int a = 0; a < 4; ++a)
#pragma unroll
            for (int b = 0; b < 4; ++b)
                acc[4 + a][b] = __builtin_amdgcn_mfma_f32_16x16x32_bf16(ag[a], bg[b], acc[4 + a][b], 0, 0, 0);
        __builtin_amdgcn_s_setprio(0);
        asm volatile("s_waitcnt vmcnt(4)");    // next tile's ksub0 halves landed
        __builtin_amdgcn_s_barrier();
    }
    __syncthreads();                           // drains DMA (incl. dummy); LDS reusable

    // ---- epilogue: bias+relu+f2bf via per-wave scratch, coalesced stores ----
    constexpr int ES = 72;                     // shorts per scratch row
    float bv[4];
#pragma unroll
    for (int b = 0; b < 4; ++b) bv[b] = bias[bn + wn * 64 + b * 16 + lane16];
    u16* scr = ((u16*)sB) + w * (16 * ES);     // 2304 B per wave
#pragma unroll
    for (int a = 0; a < 8; ++a) {
#pragma unroll
        for (int b = 0; b < 4; ++b)
#pragma unroll
            for (int r = 0; r < 4; ++r) {
                float v = fmaxf(acc[a][b][r] + bv[b], 0.f);
                scr[(quad * 4 + r) * ES + b * 16 + lane16] = f2bf(v);
            }
#pragma unroll
        for (int ch = 0; ch < 2; ++ch) {
            int row = ch * 8 + (lane >> 3), colc = (lane & 7) * 8;
            short8 v = *(const short8*)(scr + row * ES + colc);
            *(short8*)(Cc + (size_t)(bm + wm * 128 + a * 16 + row) * 1024 + bn + wn * 64 + colc) = v;
        }
    }
}

// ---------------------------------------------------------------------------
// Fused GEMM3 + coupling. NEW (this round): tall-skinny streaming form.
// B (wst, 64x1024 = 128 KB) staged to LDS ONCE; A fragments stream
// global->register (coalesced: each instr reads 16 full 64B lines); main
// loop is 32 barrier-free K-steps of {1 A-load, 4 B ds_reads, 4 MFMA}.
// Block = 128 rows, 8 waves x 16 rows, acc = 4 x f32x4 per lane.
// A-frag layout (lane16=row, quad=k-group) matches the old LDS-staged
// layout exactly, so MFMA semantics are unchanged. sst aliases the B
// buffer after the compute barrier; coupling/stats tail is verbatim.
// ---------------------------------------------------------------------------
__global__ __launch_bounds__(512)
void gemm3_coupling(const u16* __restrict__ A,    // h2 chunk [CH][1024]
                    const u16* __restrict__ Bt,   // wst [64][1024]
                    const float* __restrict__ bs, const float* __restrict__ bt,
                    float* __restrict__ x, float* __restrict__ log_det,
                    float* __restrict__ stat_sum, float* __restrict__ stat_sumsq,
                    int keep_off, int row0)
{
    constexpr int ST_STRIDE = 66;
    __shared__ u16 sB[128 * 512];                    // 128 KB: entry e = s*4+j
    __shared__ float ssum[8][64], ssum2[8][64];
    float* sst = (float*)sB;                         // 128*66*4 = 33.8 KB < 128 KB

    const int t = threadIdx.x;
    const int w = t >> 6, lane = t & 63;
    const int lane16 = lane & 15, quad = lane >> 4;
    const int bm = blockIdx.x * 128;

    // ---- stage all of B once: 128 entries (16 KB/wave, 16 gl_lds) ----
#pragma unroll
    for (int r = 0; r < 16; ++r) {
        int e = r * 8 + w;                           // s = e>>2, j = e&3
        int s = e >> 2, j = e & 3;
        const u16* g = Bt + (size_t)(j * 16 + lane16) * HH + s * 32 + quad * 8;
        gl_lds16(g, &sB[e * 512]);
    }

    f32x4 acc[4];
#pragma unroll
    for (int j = 0; j < 4; ++j) acc[j] = (f32x4){0.f, 0.f, 0.f, 0.f};

    const u16* Arow = A + (size_t)(bm + w * 16 + lane16) * HH + quad * 8;

    __syncthreads();                                 // B staged (drains DMA)

    // ---- main loop: 32 K-steps of 32, no barriers ----
#pragma unroll 4
    for (int s = 0; s < 32; ++s) {
        short8 af = *(const short8*)(Arow + s * 32);
        const u16* bb = sB + s * 2048 + lane * 8;    // entry (s*4+0), lane frag
#pragma unroll
        for (int j = 0; j < 4; ++j) {
            short8 bfr = *(const short8*)(bb + j * 512);
            acc[j] = __builtin_amdgcn_mfma_f32_16x16x32_bf16(af, bfr, acc[j], 0, 0, 0);
        }
    }
    __syncthreads();                                 // all B reads done; alias as sst

    // scatter acc -> LDS st tile (128 x 64)
#pragma unroll
    for (int j = 0; j < 4; ++j)
#pragma unroll
        for (int r = 0; r < 4; ++r)
            sst[(w * 16 + quad * 4 + r) * ST_STRIDE + j * 16 + lane16] = acc[j][r];
    __syncthreads();

    // coupling: wave w -> rows [w*16, w*16+16), lane = feature f
    const int f = lane;
    const bool is_chg = ((f & 1) != keep_off);
    const int j = f >> 1;
    float bsj = 0.f, btj = 0.f;
    if (is_chg) { bsj = bs[j]; btj = bt[j]; }

    float lsum = 0.f, lsum2 = 0.f;
    for (int i = 0; i < 16; ++i) {
        int crow = w * 16 + i;
        int grow = row0 + bm + crow;
        float xv = x[(size_t)grow * DD + f];
        float ld = 0.f;
        if (is_chg) {
            float s_raw = sst[crow * ST_STRIDE + j];
            float t_raw = sst[crow * ST_STRIDE + SPLIT + j];
            float ls = tanhf(s_raw + bsj);
            float tv = t_raw + btj;
            xv = xv * expf(ls) + tv;
            x[(size_t)grow * DD + f] = xv;
            ld = ls;
        }
        for (int off = 32; off > 0; off >>= 1) ld += __shfl_down(ld, off, 64);
        if (f == 0) log_det[grow] += ld;
        lsum  += xv;
        lsum2 += xv * xv;
    }

    ssum[w][f]  = lsum;
    ssum2[w][f] = lsum2;
    __syncthreads();
    if (t < 64) {
        float a = 0.f, b = 0.f;
#pragma unroll
        for (int g = 0; g < 8; ++g) { a += ssum[g][t]; b += ssum2[g][t]; }
        atomicAdd(stat_sum + t, a);
        atomicAdd(stat_sumsq + t, b);
    }
}

// ---------------------------------------------------------------------------
// BN normalize (scale/shift computed in-block from raw stats); optionally
// writes bf16 keep-columns of next layer's Ain.
// ---------------------------------------------------------------------------
__global__ __launch_bounds__(256)
void normalize_kernel(const float* __restrict__ xin, float* __restrict__ xout,
                      const float* __restrict__ stat_sum, const float* __restrict__ stat_sumsq,
                      const float* __restrict__ bn_w, const float* __restrict__ bn_b,
                      float* __restrict__ log_det,
                      u16* __restrict__ Ain, int off_next)
{
    __shared__ float sscale[64], sshift[64], scsum;
    int t = threadIdx.x;
    if (t < 64) {
        const float invB = 1.f / (float)BB;
        float mean = stat_sum[t] * invB;
        float var  = stat_sumsq[t] * invB - mean * mean;
        float inv  = rsqrtf(var + EPSV);
        float wv   = bn_w[t];
        float sc   = inv * wv;
        sscale[t] = sc;
        sshift[t] = bn_b[t] - mean * sc;
        float lg = logf(fabsf(wv));
        for (int off = 32; off > 0; off >>= 1) lg += __shfl_down(lg, off, 64);
        if (t == 0) scsum = lg;
    }
    __syncthreads();

    int idx = blockIdx.x * blockDim.x + t;     // over B*64/4
    int f0 = (idx & 15) * 4;
    int row = idx >> 4;
    float4 v = ((const float4*)xin)[idx];
    v.x = v.x * sscale[f0 + 0] + sshift[f0 + 0];
    v.y = v.y * sscale[f0 + 1] + sshift[f0 + 1];
    v.z = v.z * sscale[f0 + 2] + sshift[f0 + 2];
    v.w = v.w * sscale[f0 + 3] + sshift[f0 + 3];
    ((float4*)xout)[idx] = v;
    if ((idx & 15) == 0) log_det[row] += scsum;
    if (Ain) {
        float a0 = off_next ? v.y : v.x;
        float a1 = off_next ? v.w : v.z;
        ushort2 u; u.x = f2bf(a0); u.y = f2bf(a1);
        *(ushort2*)(Ain + (size_t)row * 128 + (f0 >> 1)) = u;
    }
}

// ---------------------------------------------------------------------------
extern "C" void kernel_launch(void* const* d_in, const int* in_sizes, int n_in,
                              void* d_out, int out_size, void* d_ws, size_t ws_size,
                              hipStream_t stream)
{
    const float* z    = (const float*)d_in[0];
    const float* cond = (const float*)d_in[1];
    const float* W1   = (const float*)d_in[2];
    const float* b1   = (const float*)d_in[3];
    const float* W2   = (const float*)d_in[4];
    const float* b2   = (const float*)d_in[5];
    const float* Ws   = (const float*)d_in[6];
    const float* bs   = (const float*)d_in[7];
    const float* Wt   = (const float*)d_in[8];
    const float* bt   = (const float*)d_in[9];
    const float* bn_w = (const float*)d_in[10];
    const float* bn_b = (const float*)d_in[11];

    float* out_x  = (float*)d_out;
    float* out_ld = out_x + (size_t)BB * DD;

    // ---- workspace: fixed part ~30.5 MB + h1/h2 (CH*4 KB) ----
    char* p = (char*)d_ws;
    size_t used = 0;
    auto alloc = [&](size_t bytes) { void* q = p + used; used += (bytes + 255) & ~(size_t)255; return q; };

    float* xbuf = (float*)alloc((size_t)BB * DD * 4);
    u16*   w1t  = (u16*)alloc((size_t)LL * HH * 128 * 2);
    u16*   w2t  = (u16*)alloc((size_t)LL * HH * HH * 2);
    u16*   wstt = (u16*)alloc((size_t)LL * 64 * HH * 2);
    u16*   Ain  = (u16*)alloc((size_t)BB * 128 * 2);
    float* stat_sum   = (float*)alloc(64 * 4);
    float* stat_sumsq = (float*)alloc(64 * 4);

    int CH = BB;
    while (CH > 8192 && used + (size_t)CH * 4096 + 4096 > ws_size) CH >>= 1;
    u16* h1 = (u16*)alloc((size_t)CH * HH * 2);
    u16* h2 = (u16*)alloc((size_t)CH * HH * 2);

    // ---- init ----
    hipMemcpyAsync(xbuf, z, (size_t)BB * DD * sizeof(float), hipMemcpyDeviceToDevice, stream);
    hipMemsetAsync(out_ld, 0, (size_t)BB * sizeof(float), stream);

    transpose_cvt_kernel<<<dim3(128/32, HH/32, LL), 256, 0, stream>>>(
        W1, w1t, NIN, HH, 128, (long long)NIN * HH, (long long)HH * 128);
    transpose_cvt_kernel<<<dim3(HH/32, HH/32, LL), 256, 0, stream>>>(
        W2, w2t, HH, HH, HH, (long long)HH * HH, (long long)HH * HH);
    transpose_cvt_kernel<<<dim3(HH/32, SPLIT/32, LL), 256, 0, stream>>>(
        Ws, wstt, HH, SPLIT, HH, (long long)HH * SPLIT, (long long)64 * HH);
    transpose_cvt_kernel<<<dim3(HH/32, SPLIT/32, LL), 256, 0, stream>>>(
        Wt, wstt + (size_t)SPLIT * HH, HH, SPLIT, HH, (long long)HH * SPLIT, (long long)64 * HH);

    init_ain_cond_kernel<<<BB * 96 / 256, 256, 0, stream>>>(cond, Ain);
    build_keep_kernel<<<BB * 32 / 256, 256, 0, stream>>>(xbuf, Ain, 0);

    for (int l = 0; l < LL; ++l) {
        const int off = l & 1;
        hipMemsetAsync(stat_sum, 0, 2 * 64 * sizeof(float), stream);

        for (int c = 0; c < BB / CH; ++c) {
            const int row0 = c * CH;

            // GEMM1: h1 = relu(Ain @ W1t^T + b1)   M=CH, K=128
            gemm_tiled<<<(CH / 256) * 4, 512, 0, stream>>>(
                Ain + (size_t)row0 * 128, w1t + (size_t)l * HH * 128,
                b1 + (size_t)l * HH, h1, 128);

            // GEMM2: h2 = relu(h1 @ W2t^T + b2)    M=CH, K=1024
            gemm_tiled<<<(CH / 256) * 4, 512, 0, stream>>>(
                h1, w2t + (size_t)l * HH * HH,
                b2 + (size_t)l * HH, h2, HH);

            // GEMM3 + coupling fused (streaming, B-in-LDS-once)
            gemm3_coupling<<<CH / 128, 512, 0, stream>>>(
                h2, wstt + (size_t)l * 64 * HH,
                bs + (size_t)l * SPLIT, bt + (size_t)l * SPLIT,
                xbuf, out_ld, stat_sum, stat_sumsq, off, row0);
        }

        float* xout = (l == LL - 1) ? out_x : xbuf;
        u16* ain_next = (l < LL - 1) ? Ain : nullptr;
        normalize_kernel<<<(BB * DD / 4) / 256, 256, 0, stream>>>(
            xbuf, xout, stat_sum, stat_sumsq,
            bn_w + (size_t)l * DD, bn_b + (size_t)l * DD,
            out_ld, ain_next, (l + 1) & 1);
    }
}